// Round 12
// baseline (255.483 us; speedup 1.0000x reference)
//
#include <hip/hip_runtime.h>

typedef _Float16 half8_t __attribute__((ext_vector_type(8)));
typedef _Float16 half4_t __attribute__((ext_vector_type(4)));
typedef float    float4_t __attribute__((ext_vector_type(4)));

#define DIM 768

// async global->LDS, 16B per lane; LDS dest is wave-uniform base + lane*16
#define GLOAD16(g, l) __builtin_amdgcn_global_load_lds(                        \
    (const __attribute__((address_space(1))) void*)(g),                        \
    (__attribute__((address_space(3))) void*)(l), 16, 0, 0)

#define MFMA16(a, b, c) __builtin_amdgcn_mfma_f32_16x16x32_f16((a), (b), (c), 0, 0, 0)

// ---------------------------------------------------------------------------
// one fused cast launch: xq (3,145,728 half8) | xkv (786,432) | weights
// ---------------------------------------------------------------------------
__global__ __launch_bounds__(256) void cast_all(
    const float* __restrict__ xq,  const float* __restrict__ xkv,
    const float* __restrict__ Wq,  const float* __restrict__ Wk,
    const float* __restrict__ Wv,  const float* __restrict__ Wo,
    _Float16* __restrict__ dq, _Float16* __restrict__ dkv,
    _Float16* __restrict__ dW /* 4 matrices contiguous */)
{
    int i = blockIdx.x * 256 + threadIdx.x;    // grid 16512*256 = 4,227,072
    const float* s; _Float16* d; int off;
    if (i < 3145728)      { s = xq;  d = dq;  off = i; }
    else if (i < 3932160) { s = xkv; d = dkv; off = i - 3145728; }
    else {
        int j = i - 3932160;                   // 0..294911
        int w = j / 73728;  off = j - w * 73728;
        s = (w == 0) ? Wq : (w == 1) ? Wk : (w == 2) ? Wv : Wo;
        d = dW + (size_t)w * 589824;
    }
    float4_t f0 = *(const float4_t*)&s[(size_t)off * 8];
    float4_t f1 = *(const float4_t*)&s[(size_t)off * 8 + 4];
    half8_t h;
    #pragma unroll
    for (int e = 0; e < 4; ++e) { h[e] = (_Float16)f0[e]; h[e + 4] = (_Float16)f1[e]; }
    *(half8_t*)&d[(size_t)off * 8] = h;
}

// ---------------------------------------------------------------------------
// gemm_hi — HIGH-OCCUPANCY core (the untested axis): 128x128 tile, BK=32,
// 24 K-tiles, 256 thr = 4 waves (2x2), per-wave C 64x64 (acc[4][4]).
// LDS: 3 slots x 16KB = 48KB + launch_bounds(256,3) -> 3 blocks/CU
// (12 waves/CU): independent barrier domains cover each other's stalls
// (m114 mechanism; every prior variant was 1 block/CU and plateaued).
// Chunk-transposed conflict-free layout (refcheck-proven r10/r11):
// chunk = 1KB = 16 rows x 32 halves, slot g holds (row=g&15, koct=g>>4);
// A chunks 0..7, B chunks 8..15; frag read = chunk_base + lane*16B.
// Cadence per tile t (r9-proven invariants, 1 barrier/tile):
//   ds_read 8 b128 ; issue STAGE(t+2) -> slot (t+2)%3 (4 gloads/thread) ;
//   lgkmcnt(0)+sched_barrier ; 16 MFMA (setprio) ; vmcnt(4) counted ; barrier.
// Hazards: (a) slot s is overwritten by stages issued during tile t+1
//   (tile t+3 -> slot t%3); every wave's reads of s completed before it
//   passed tile t's boundary barrier (MFMA requires lgkmcnt(0)). ✓
// (b) vmcnt(4) at boundary of t leaves only tile-(t+2) loads outstanding ->
//   tile t+1 fully landed. Tail: t=21 vmcnt(4) covers t22; t=22 vmcnt(0). ✓
// ---------------------------------------------------------------------------
__device__ __forceinline__ void gemm_hi(const _Float16* __restrict__ A,
                                        const _Float16* __restrict__ W,
                                        int row0, int col0,
                                        _Float16* lds, float4_t acc[4][4])
{
    const int tid  = threadIdx.x;
    const int wid  = tid >> 6, lane = tid & 63;
    const int wr   = wid >> 1, wc = wid & 1;

    // staging: wave wid owns A chunks {2wid,2wid+1}, B chunks {2wid,2wid+1}
    const int srow = 2 * wid * 16 + (lane & 15);
    const int sk   = (lane >> 4) * 8;
    const _Float16* As0 = A + (size_t)(row0 + srow) * DIM + sk;
    const _Float16* As1 = As0 + (size_t)16 * DIM;
    const _Float16* Bs0 = W + (size_t)(col0 + srow) * DIM + sk;
    const _Float16* Bs1 = Bs0 + (size_t)16 * DIM;

#define STAGE(t, s) do {                                                       \
        GLOAD16(As0 + (t) * 32, &lds[(s) * 8192 + (2*wid    ) * 512]);         \
        GLOAD16(As1 + (t) * 32, &lds[(s) * 8192 + (2*wid + 1) * 512]);         \
        GLOAD16(Bs0 + (t) * 32, &lds[(s) * 8192 + 4096 + (2*wid    ) * 512]);  \
        GLOAD16(Bs1 + (t) * 32, &lds[(s) * 8192 + 4096 + (2*wid + 1) * 512]);  \
    } while (0)

    const int ab = (4 * wr) * 512 + lane * 8;        // + mi*512
    const int bb = 4096 + (4 * wc) * 512 + lane * 8; // + ni*512

    // prologue: tile0 -> slot0, tile1 -> slot1
    STAGE(0, 0);
    STAGE(1, 1);
    asm volatile("s_waitcnt vmcnt(4)" ::: "memory");   // tile0 landed
    __builtin_amdgcn_s_barrier();
    __builtin_amdgcn_sched_barrier(0);

    int s = 0, s2 = 2;
    for (int t = 0; t < 24; ++t) {
        const _Float16* sl = &lds[s * 8192];

        half8_t af[4], bf[4];
        #pragma unroll
        for (int mi = 0; mi < 4; ++mi)
            af[mi] = *(const half8_t*)&sl[ab + mi * 512];
        #pragma unroll
        for (int ni = 0; ni < 4; ++ni)
            bf[ni] = *(const half8_t*)&sl[bb + ni * 512];
        if (t < 22) STAGE(t + 2, s2);

        asm volatile("s_waitcnt lgkmcnt(0)" ::: "memory");
        __builtin_amdgcn_sched_barrier(0);
        __builtin_amdgcn_s_setprio(1);
        #pragma unroll
        for (int mi = 0; mi < 4; ++mi)
            #pragma unroll
            for (int ni = 0; ni < 4; ++ni)
                acc[mi][ni] = MFMA16(af[mi], bf[ni], acc[mi][ni]);
        __builtin_amdgcn_s_setprio(0);
        __builtin_amdgcn_sched_barrier(0);

        if (t < 23) {
            if (t < 22) asm volatile("s_waitcnt vmcnt(4)" ::: "memory");
            else        asm volatile("s_waitcnt vmcnt(0)" ::: "memory");
            __builtin_amdgcn_s_barrier();
            __builtin_amdgcn_sched_barrier(0);
        }
        s  = (s  == 2) ? 0 : s  + 1;
        s2 = (s2 == 2) ? 0 : s2 + 1;
    }
#undef STAGE
}

// ---------------------------------------------------------------------------
// Fused q/k/v projection on gemm_hi: 2304 blocks (128x128 tiles).
//   bid <  1536 : q = elu1(xq @ Wq.T)   (256 row-blocks x 6)
//   1536..1919  : k = elu1(xkv @ Wk.T)  ( 64 row-blocks x 6)
//   1920..2303  : v =      xkv @ Wv.T
// ---------------------------------------------------------------------------
__global__ __launch_bounds__(256, 3) void proj_qkv(
    const _Float16* __restrict__ xq16, const _Float16* __restrict__ xkv16,
    const _Float16* __restrict__ Wq16, const _Float16* __restrict__ Wk16,
    const _Float16* __restrict__ Wv16,
    _Float16* __restrict__ q16, _Float16* __restrict__ k16,
    _Float16* __restrict__ v16)
{
    __shared__ __align__(16) _Float16 lds[3 * 8192];   // 49152 B -> 3 blocks/CU

    const int cpx = gridDim.x >> 3;                    // 2304/8 = 288
    int bid = (blockIdx.x & 7) * cpx + (blockIdx.x >> 3);

    const _Float16 *A, *W; _Float16* O; bool elu;
    int brow, bcol;
    if (bid < 1536) {
        A = xq16; W = Wq16; O = q16; elu = true;
        brow = bid / 6; bcol = bid - brow * 6;
    } else {
        int u = bid - 1536;
        int mat = u / 384;  u -= mat * 384;
        A = xkv16; W = mat ? Wv16 : Wk16; O = mat ? v16 : k16; elu = !mat;
        brow = u / 6; bcol = u - brow * 6;
    }
    const int row0 = brow * 128, col0 = bcol * 128;

    float4_t acc[4][4] = {};
    gemm_hi(A, W, row0, col0, lds, acc);

    const int wid = threadIdx.x >> 6, lane = threadIdx.x & 63;
    const int wr = wid >> 1, wc = wid & 1, lr = lane & 15, lkg = lane >> 4;
    #pragma unroll
    for (int mi = 0; mi < 4; ++mi) {
        #pragma unroll
        for (int ni = 0; ni < 4; ++ni) {
            #pragma unroll
            for (int e = 0; e < 4; ++e) {
                int r = row0 + wr * 64 + mi * 16 + lkg * 4 + e;
                int c = col0 + wc * 64 + ni * 16 + lr;
                float v = acc[mi][ni][e];
                if (elu) v = (v > 0.0f) ? (v + 1.0f) : __expf(v);  // elu(x)+1
                O[(size_t)r * DIM + c] = (_Float16)v;
            }
        }
    }
}

// ---------------------------------------------------------------------------
// gemm_r4 — r9's measured-best core (control arm, verbatim):
// 256x128, BK=64, 8 waves, 3 slots (147KB), 2 phases + counted vmcnt(6).
// ---------------------------------------------------------------------------
__device__ __forceinline__ void gemm_r4(const _Float16* __restrict__ A,
                                        const _Float16* __restrict__ W,
                                        int row0, int col0,
                                        _Float16* lds, float4_t acc[8][2])
{
    const int tid  = threadIdx.x;
    const int wid  = tid >> 6, lane = tid & 63;
    const int wr   = wid >> 2;
    const int wc   = wid & 3;
    const int lr   = lane & 15;
    const int lkg  = lane >> 4;
    const int x    = lr & 7;

    const int  srow = wid * 8 + (lane >> 3);
    const int  sg   = ((lane & 7) ^ (lane >> 3)) * 8;
    const _Float16* Ast = A + (size_t)(row0 + srow) * DIM + sg;
    const _Float16* Bst = W + (size_t)(col0 + srow) * DIM + sg;

#define LDSA(s) (&lds[(s) * 24576])
#define LDSB(s) (&lds[(s) * 24576 + 16384])
#define STAGE_A(t, s, j) GLOAD16(Ast + (size_t)(t) * 64 + (size_t)(j) * 64 * DIM, \
                                 LDSA(s) + (j) * 4096 + wid * 512)
#define STAGE_B(t, s, j) GLOAD16(Bst + (size_t)(t) * 64 + (size_t)(j) * 64 * DIM, \
                                 LDSB(s) + (j) * 4096 + wid * 512)

    const int ard = (wr * 128 + lr) * 64;
    const int brd = (wc * 32 + lr) * 64;
    const int g0  = (lkg ^ x) * 8;
    const int g1  = g0 ^ 32;

    STAGE_A(0, 0, 0); STAGE_A(0, 0, 1); STAGE_A(0, 0, 2); STAGE_A(0, 0, 3);
    STAGE_B(0, 0, 0); STAGE_B(0, 0, 1);
    STAGE_A(1, 1, 0); STAGE_A(1, 1, 1); STAGE_A(1, 1, 2); STAGE_A(1, 1, 3);
    STAGE_B(1, 1, 0); STAGE_B(1, 1, 1);
    asm volatile("s_waitcnt vmcnt(6)" ::: "memory");
    __builtin_amdgcn_s_barrier();

    int s = 0, s2 = 2;
    for (int t = 0; t < 12; ++t) {
        const _Float16* Asl = LDSA(s);
        const _Float16* Bsl = LDSB(s);
        const bool pf = (t < 10);

        half8_t bf[2][2];
        bf[0][0] = *(const half8_t*)&Bsl[brd + g0];
        bf[0][1] = *(const half8_t*)&Bsl[brd + g1];
        bf[1][0] = *(const half8_t*)&Bsl[brd + 1024 + g0];
        bf[1][1] = *(const half8_t*)&Bsl[brd + 1024 + g1];
        half8_t af0[4][2];
        #pragma unroll
        for (int i = 0; i < 4; ++i) {
            af0[i][0] = *(const half8_t*)&Asl[ard + i * 1024 + g0];
            af0[i][1] = *(const half8_t*)&Asl[ard + i * 1024 + g1];
        }
        if (pf) { STAGE_A(t + 2, s2, 0); STAGE_A(t + 2, s2, 1); STAGE_A(t + 2, s2, 2); }
        __builtin_amdgcn_s_barrier();
        asm volatile("s_waitcnt lgkmcnt(0)" ::: "memory");
        __builtin_amdgcn_sched_barrier(0);
        __builtin_amdgcn_s_setprio(1);
        #pragma unroll
        for (int i = 0; i < 4; ++i)
            #pragma unroll
            for (int ni = 0; ni < 2; ++ni) {
                acc[i][ni] = MFMA16(af0[i][0], bf[ni][0], acc[i][ni]);
                acc[i][ni] = MFMA16(af0[i][1], bf[ni][1], acc[i][ni]);
            }
        __builtin_amdgcn_s_setprio(0);
        __builtin_amdgcn_sched_barrier(0);
        __builtin_amdgcn_s_barrier();

        half8_t af1[4][2];
        #pragma unroll
        for (int i = 0; i < 4; ++i) {
            af1[i][0] = *(const half8_t*)&Asl[ard + 4096 + i * 1024 + g0];
            af1[i][1] = *(const half8_t*)&Asl[ard + 4096 + i * 1024 + g1];
        }
        if (pf) { STAGE_A(t + 2, s2, 3); STAGE_B(t + 2, s2, 0); STAGE_B(t + 2, s2, 1); }
        __builtin_amdgcn_s_barrier();
        asm volatile("s_waitcnt lgkmcnt(0)" ::: "memory");
        __builtin_amdgcn_sched_barrier(0);
        __builtin_amdgcn_s_setprio(1);
        #pragma unroll
        for (int i = 0; i < 4; ++i)
            #pragma unroll
            for (int ni = 0; ni < 2; ++ni) {
                acc[4 + i][ni] = MFMA16(af1[i][0], bf[ni][0], acc[4 + i][ni]);
                acc[4 + i][ni] = MFMA16(af1[i][1], bf[ni][1], acc[4 + i][ni]);
            }
        __builtin_amdgcn_s_setprio(0);
        __builtin_amdgcn_sched_barrier(0);

        if (t < 11) {
            if (pf) asm volatile("s_waitcnt vmcnt(6)" ::: "memory");
            else    asm volatile("s_waitcnt vmcnt(0)" ::: "memory");
            __builtin_amdgcn_s_barrier();
        }
        s  = (s  == 2) ? 0 : s  + 1;
        s2 = (s2 == 2) ? 0 : s2 + 1;
    }
#undef LDSA
#undef LDSB
#undef STAGE_A
#undef STAGE_B
}

// ---------------------------------------------------------------------------
// out = attn16 @ Wo.T + bo  (fp32 output), 768 blocks — r9 control arm
// ---------------------------------------------------------------------------
__global__ __launch_bounds__(512) void out_proj(
    const _Float16* __restrict__ a16, const _Float16* __restrict__ Wo16,
    const float* __restrict__ bo, float* __restrict__ out)
{
    __shared__ __align__(16) _Float16 lds[3 * 24576];

    const int cpx = gridDim.x >> 3;                     // 768/8 = 96
    int bid = (blockIdx.x & 7) * cpx + (blockIdx.x >> 3);
    const int brow = bid / 6, bcol = bid - brow * 6;
    const int row0 = brow * 256, col0 = bcol * 128;

    float4_t acc[8][2] = {};
    gemm_r4(a16, Wo16, row0, col0, lds, acc);

    const int wid = threadIdx.x >> 6, lane = threadIdx.x & 63;
    const int wr = wid >> 2, wc = wid & 3, lr = lane & 15, lkg = lane >> 4;
    #pragma unroll
    for (int mi = 0; mi < 8; ++mi) {
        #pragma unroll
        for (int ni = 0; ni < 2; ++ni) {
            #pragma unroll
            for (int e = 0; e < 4; ++e) {
                int r = row0 + wr * 128 + mi * 16 + lkg * 4 + e;
                int c = col0 + wc * 32 + ni * 16 + lr;
                out[(size_t)r * DIM + c] = acc[mi][ni][e] + bo[c];
            }
        }
    }
}

// ---------------------------------------------------------------------------
// kv_reduce: per (b,h): kvh[e][d] = sum_n v[n,e]*k[n,d];  ksum[d] = sum_n k[n,d]
// ---------------------------------------------------------------------------
__global__ __launch_bounds__(256) void kv_reduce(const _Float16* __restrict__ k16,
                                                 const _Float16* __restrict__ v16,
                                                 float* __restrict__ kvh,
                                                 float* __restrict__ ksum)
{
    __shared__ __align__(16) _Float16 K[128][64];
    __shared__ __align__(16) _Float16 V[128][64];
    const int chunk = blockIdx.x;   // 0..7
    const int bh    = blockIdx.y;   // 0..95
    const int b = bh / 12, h = bh % 12;
    const int tid = threadIdx.x;

    const size_t base = ((size_t)b * 1024 + (size_t)chunk * 128) * DIM + h * 64;
    #pragma unroll
    for (int j = 0; j < 4; ++j) {
        int idx = j * 256 + tid;
        int r = idx >> 3, c = (idx & 7) * 8;
        *(half8_t*)&K[r][c] = *(const half8_t*)&k16[base + (size_t)r * DIM + c];
        *(half8_t*)&V[r][c] = *(const half8_t*)&v16[base + (size_t)r * DIM + c];
    }
    __syncthreads();

    const int d0 = (tid & 15) * 4;
    const int e0 = (tid >> 4) * 4;
    float acc[4][4] = {};
    #pragma unroll 4
    for (int n = 0; n < 128; ++n) {
        half4_t kd = *(const half4_t*)&K[n][d0];
        half4_t ve = *(const half4_t*)&V[n][e0];
        #pragma unroll
        for (int i = 0; i < 4; ++i)
            #pragma unroll
            for (int j = 0; j < 4; ++j)
                acc[i][j] += (float)ve[i] * (float)kd[j];
    }
    float* kvp = kvh + (size_t)bh * 64 * 64;
    #pragma unroll
    for (int i = 0; i < 4; ++i)
        #pragma unroll
        for (int j = 0; j < 4; ++j)
            atomicAdd(&kvp[(e0 + i) * 64 + d0 + j], acc[i][j]);

    if (tid < 64) {
        float s = 0.0f;
        for (int n = 0; n < 128; ++n) s += (float)K[n][tid];
        atomicAdd(&ksum[bh * 64 + tid], s);
    }
}

// ---------------------------------------------------------------------------
// attn: z = 1/(q . ksum + 1e-6); attn = (q @ kv) * z   (in-place on q16)
// ---------------------------------------------------------------------------
__global__ __launch_bounds__(256) void attn_kernel(_Float16* __restrict__ q16,
                                                   const float* __restrict__ kvh,
                                                   const float* __restrict__ ksum)
{
    __shared__ __align__(16) _Float16 Q[128][72];
    __shared__ __align__(16) _Float16 Bv[64][72];
    __shared__ float S[64];
    __shared__ float Z[128];

    const int h    = blockIdx.x;        // 0..11
    const int rb   = blockIdx.y;        // 0..255
    const int row0 = rb * 128;
    const int b    = row0 >> 12;
    const int bh   = b * 12 + h;
    const int tid  = threadIdx.x;

    #pragma unroll
    for (int j = 0; j < 4; ++j) {
        int idx = j * 256 + tid;
        int r = idx >> 3, c = (idx & 7) * 8;
        *(half8_t*)&Q[r][c] =
            *(const half8_t*)&q16[(size_t)(row0 + r) * DIM + h * 64 + c];
    }
    #pragma unroll
    for (int j = 0; j < 4; ++j) {
        int idx = j * 256 + tid;
        int r = idx >> 4, c = (idx & 15) * 4;
        float4_t f = *(const float4_t*)&kvh[((size_t)bh * 64 + r) * 64 + c];
        half4_t hh;
        #pragma unroll
        for (int e = 0; e < 4; ++e) hh[e] = (_Float16)f[e];
        *(half4_t*)&Bv[r][c] = hh;
    }
    if (tid < 64) S[tid] = ksum[bh * 64 + tid];
    __syncthreads();

    if (tid < 128) {
        float dot = 0.0f;
        #pragma unroll 8
        for (int d = 0; d < 64; ++d) dot += (float)Q[tid][d] * S[d];
        Z[tid] = 1.0f / (dot + 1e-6f);
    }
    __syncthreads();

    const int w = tid >> 6, lane = tid & 63;
    const int lr = lane & 15, lkg = lane >> 4;
    float4_t acc[2][4] = {};
    #pragma unroll
    for (int kc = 0; kc < 2; ++kc) {
        half8_t aF[2], bF[4];
        #pragma unroll
        for (int mi = 0; mi < 2; ++mi)
            aF[mi] = *(const half8_t*)&Q[w * 32 + mi * 16 + lr][kc * 32 + lkg * 8];
        #pragma unroll
        for (int ni = 0; ni < 4; ++ni)
            bF[ni] = *(const half8_t*)&Bv[ni * 16 + lr][kc * 32 + lkg * 8];
        #pragma unroll
        for (int mi = 0; mi < 2; ++mi)
            #pragma unroll
            for (int ni = 0; ni < 4; ++ni)
                acc[mi][ni] = MFMA16(aF[mi], bF[ni], acc[mi][ni]);
    }
    #pragma unroll
    for (int mi = 0; mi < 2; ++mi) {
        #pragma unroll
        for (int ni = 0; ni < 4; ++ni) {
            #pragma unroll
            for (int e = 0; e < 4; ++e) {
                int r = w * 32 + mi * 16 + lkg * 4 + e;
                float v = acc[mi][ni][e] * Z[r];
                q16[(size_t)(row0 + r) * DIM + h * 64 + ni * 16 + lr] = (_Float16)v;
            }
        }
    }
}

// ---------------------------------------------------------------------------
extern "C" void kernel_launch(void* const* d_in, const int* in_sizes, int n_in,
                              void* d_out, int out_size, void* d_ws, size_t ws_size,
                              hipStream_t stream)
{
    const float* xq  = (const float*)d_in[0];  // [8,4096,768]
    const float* xkv = (const float*)d_in[1];  // [8,1024,768]
    const float* Wq  = (const float*)d_in[2];
    const float* Wk  = (const float*)d_in[3];
    const float* Wv  = (const float*)d_in[4];
    const float* Wo  = (const float*)d_in[5];
    const float* bo  = (const float*)d_in[6];

    // ---- workspace layout (~69 MB) ----
    char* ws = (char*)d_ws;
    const size_t SZ_Q16   = (size_t)32768 * 768 * 2;   // 50,331,648
    const size_t SZ_XKV16 = (size_t)8192 * 768 * 2;    // 12,582,912
    const size_t SZ_W16   = (size_t)768 * 768 * 2;     //  1,179,648
    const size_t SZ_KVH   = (size_t)96 * 64 * 64 * 4;  //  1,572,864
    const size_t SZ_KSUM  = (size_t)96 * 64 * 4;       //     24,576

    _Float16* q16   = (_Float16*)(ws);
    _Float16* xkv16 = (_Float16*)(ws + SZ_Q16);
    _Float16* Wq16  = (_Float16*)(ws + SZ_Q16 + SZ_XKV16);            // 4 contiguous
    _Float16* Wk16  = (_Float16*)(ws + SZ_Q16 + SZ_XKV16 + SZ_W16);
    _Float16* Wv16  = (_Float16*)(ws + SZ_Q16 + SZ_XKV16 + 2 * SZ_W16);
    _Float16* Wo16  = (_Float16*)(ws + SZ_Q16 + SZ_XKV16 + 3 * SZ_W16);
    float*    kvh   = (float*)   (ws + SZ_Q16 + SZ_XKV16 + 4 * SZ_W16);
    float*    ksum  = (float*)   (ws + SZ_Q16 + SZ_XKV16 + 4 * SZ_W16 + SZ_KVH);

    // ---- d_out aliasing: xq16 consumed by proj_qkv; k16/v16 by kv_reduce;
    //      all dead before out_proj overwrites d_out. ----
    char* ob = (char*)d_out;
    _Float16* xq16 = (_Float16*)(ob);                       // 50,331,648
    _Float16* k16  = (_Float16*)(ob + 50331648);            // 12,582,912
    _Float16* v16  = (_Float16*)(ob + 50331648 + 12582912); // 12,582,912
    float*    out  = (float*)d_out;

    // 1) one fused cast launch + kv accumulator clear
    cast_all<<<16512, 256, 0, stream>>>(xq, xkv, Wq, Wk, Wv, Wo,
                                        xq16, xkv16, Wq16);
    hipMemsetAsync(kvh, 0, SZ_KVH + SZ_KSUM, stream);

    // 2) fused projections (hi-occupancy experimental core)
    proj_qkv<<<2304, 256, 0, stream>>>(xq16, xkv16, Wq16, Wk16, Wv16,
                                       q16, k16, v16);

    // 3) linear attention
    kv_reduce<<<dim3(8, 96), 256, 0, stream>>>(k16, v16, kvh, ksum);
    attn_kernel<<<dim3(12, 256), 256, 0, stream>>>(q16, kvh, ksum);

    // 4) out = attn @ Wo.T + bo  (fp32 output, r9 control core)
    out_proj<<<768, 512, 0, stream>>>(q16, Wo16, bo, out);
}

// Round 13
// 221.890 us; speedup vs baseline: 1.1514x; 1.1514x over previous
//
#include <hip/hip_runtime.h>

typedef _Float16 half8_t __attribute__((ext_vector_type(8)));
typedef _Float16 half4_t __attribute__((ext_vector_type(4)));
typedef float    float4_t __attribute__((ext_vector_type(4)));

#define DIM 768

// async global->LDS, 16B per lane; LDS dest is wave-uniform base + lane*16
#define GLOAD16(g, l) __builtin_amdgcn_global_load_lds(                        \
    (const __attribute__((address_space(1))) void*)(g),                        \
    (__attribute__((address_space(3))) void*)(l), 16, 0, 0)

#define MFMA16(a, b, c) __builtin_amdgcn_mfma_f32_16x16x32_f16((a), (b), (c), 0, 0, 0)

// ---------------------------------------------------------------------------
// one fused cast launch: xq (3,145,728 half8) | xkv (786,432) | weights
// (4 x 73,728) | zero kvh+ksum (99,840 float4) — memset folded in.
// grid = 16902 * 256
// ---------------------------------------------------------------------------
__global__ __launch_bounds__(256) void cast_all(
    const float* __restrict__ xq,  const float* __restrict__ xkv,
    const float* __restrict__ Wq,  const float* __restrict__ Wk,
    const float* __restrict__ Wv,  const float* __restrict__ Wo,
    _Float16* __restrict__ dq, _Float16* __restrict__ dkv,
    _Float16* __restrict__ dW /* 4 matrices contiguous */,
    float* __restrict__ kvz /* kvh+ksum region, 399,360 floats */)
{
    int i = blockIdx.x * 256 + threadIdx.x;
    if (i >= 4227072) {                        // zero kvh/ksum tail
        int z = i - 4227072;
        if (z < 99840) {
            float4_t zf = {0.f, 0.f, 0.f, 0.f};
            *(float4_t*)&kvz[(size_t)z * 4] = zf;
        }
        return;
    }
    const float* s; _Float16* d; int off;
    if (i < 3145728)      { s = xq;  d = dq;  off = i; }
    else if (i < 3932160) { s = xkv; d = dkv; off = i - 3145728; }
    else {
        int j = i - 3932160;                   // 0..294911
        int w = j / 73728;  off = j - w * 73728;
        s = (w == 0) ? Wq : (w == 1) ? Wk : (w == 2) ? Wv : Wo;
        d = dW + (size_t)w * 589824;
    }
    float4_t f0 = *(const float4_t*)&s[(size_t)off * 8];
    float4_t f1 = *(const float4_t*)&s[(size_t)off * 8 + 4];
    half8_t h;
    #pragma unroll
    for (int e = 0; e < 4; ++e) { h[e] = (_Float16)f0[e]; h[e + 4] = (_Float16)f1[e]; }
    *(half8_t*)&d[(size_t)off * 8] = h;
}

// ---------------------------------------------------------------------------
// gemm_r4 — the measured-best core (613 TF band, r4/r9 verbatim):
// Tile 256x128, BK=64, 512 thr = 8 waves (2M x 4N), per-wave C 128x32.
// 3 LDS slots (48KB each), stage t+2 while computing t, counted vmcnt(6)
// never 0 until tail, 2 phases + setprio, XOR-granule swizzle (0 conflicts).
// ---------------------------------------------------------------------------
__device__ __forceinline__ void gemm_r4(const _Float16* __restrict__ A,
                                        const _Float16* __restrict__ W,
                                        int row0, int col0,
                                        _Float16* lds, float4_t acc[8][2])
{
    const int tid  = threadIdx.x;
    const int wid  = tid >> 6, lane = tid & 63;
    const int wr   = wid >> 2;
    const int wc   = wid & 3;
    const int lr   = lane & 15;
    const int lkg  = lane >> 4;
    const int x    = lr & 7;

    const int  srow = wid * 8 + (lane >> 3);
    const int  sg   = ((lane & 7) ^ (lane >> 3)) * 8;
    const _Float16* Ast = A + (size_t)(row0 + srow) * DIM + sg;
    const _Float16* Bst = W + (size_t)(col0 + srow) * DIM + sg;

#define LDSA(s) (&lds[(s) * 24576])
#define LDSB(s) (&lds[(s) * 24576 + 16384])
#define STAGE_A(t, s, j) GLOAD16(Ast + (size_t)(t) * 64 + (size_t)(j) * 64 * DIM, \
                                 LDSA(s) + (j) * 4096 + wid * 512)
#define STAGE_B(t, s, j) GLOAD16(Bst + (size_t)(t) * 64 + (size_t)(j) * 64 * DIM, \
                                 LDSB(s) + (j) * 4096 + wid * 512)

    const int ard = (wr * 128 + lr) * 64;
    const int brd = (wc * 32 + lr) * 64;
    const int g0  = (lkg ^ x) * 8;
    const int g1  = g0 ^ 32;

    STAGE_A(0, 0, 0); STAGE_A(0, 0, 1); STAGE_A(0, 0, 2); STAGE_A(0, 0, 3);
    STAGE_B(0, 0, 0); STAGE_B(0, 0, 1);
    STAGE_A(1, 1, 0); STAGE_A(1, 1, 1); STAGE_A(1, 1, 2); STAGE_A(1, 1, 3);
    STAGE_B(1, 1, 0); STAGE_B(1, 1, 1);
    asm volatile("s_waitcnt vmcnt(6)" ::: "memory");
    __builtin_amdgcn_s_barrier();

    int s = 0, s2 = 2;
    for (int t = 0; t < 12; ++t) {
        const _Float16* Asl = LDSA(s);
        const _Float16* Bsl = LDSB(s);
        const bool pf = (t < 10);

        // ================= phase 0 : mi 0..3 =================
        half8_t bf[2][2];
        bf[0][0] = *(const half8_t*)&Bsl[brd + g0];
        bf[0][1] = *(const half8_t*)&Bsl[brd + g1];
        bf[1][0] = *(const half8_t*)&Bsl[brd + 1024 + g0];
        bf[1][1] = *(const half8_t*)&Bsl[brd + 1024 + g1];
        half8_t af0[4][2];
        #pragma unroll
        for (int i = 0; i < 4; ++i) {
            af0[i][0] = *(const half8_t*)&Asl[ard + i * 1024 + g0];
            af0[i][1] = *(const half8_t*)&Asl[ard + i * 1024 + g1];
        }
        if (pf) { STAGE_A(t + 2, s2, 0); STAGE_A(t + 2, s2, 1); STAGE_A(t + 2, s2, 2); }
        __builtin_amdgcn_s_barrier();
        asm volatile("s_waitcnt lgkmcnt(0)" ::: "memory");
        __builtin_amdgcn_sched_barrier(0);
        __builtin_amdgcn_s_setprio(1);
        #pragma unroll
        for (int i = 0; i < 4; ++i)
            #pragma unroll
            for (int ni = 0; ni < 2; ++ni) {
                acc[i][ni] = MFMA16(af0[i][0], bf[ni][0], acc[i][ni]);
                acc[i][ni] = MFMA16(af0[i][1], bf[ni][1], acc[i][ni]);
            }
        __builtin_amdgcn_s_setprio(0);
        __builtin_amdgcn_sched_barrier(0);
        __builtin_amdgcn_s_barrier();

        // ================= phase 1 : mi 4..7 =================
        half8_t af1[4][2];
        #pragma unroll
        for (int i = 0; i < 4; ++i) {
            af1[i][0] = *(const half8_t*)&Asl[ard + 4096 + i * 1024 + g0];
            af1[i][1] = *(const half8_t*)&Asl[ard + 4096 + i * 1024 + g1];
        }
        if (pf) { STAGE_A(t + 2, s2, 3); STAGE_B(t + 2, s2, 0); STAGE_B(t + 2, s2, 1); }
        __builtin_amdgcn_s_barrier();
        asm volatile("s_waitcnt lgkmcnt(0)" ::: "memory");
        __builtin_amdgcn_sched_barrier(0);
        __builtin_amdgcn_s_setprio(1);
        #pragma unroll
        for (int i = 0; i < 4; ++i)
            #pragma unroll
            for (int ni = 0; ni < 2; ++ni) {
                acc[4 + i][ni] = MFMA16(af1[i][0], bf[ni][0], acc[4 + i][ni]);
                acc[4 + i][ni] = MFMA16(af1[i][1], bf[ni][1], acc[4 + i][ni]);
            }
        __builtin_amdgcn_s_setprio(0);
        __builtin_amdgcn_sched_barrier(0);

        if (t < 11) {
            if (pf) asm volatile("s_waitcnt vmcnt(6)" ::: "memory");
            else    asm volatile("s_waitcnt vmcnt(0)" ::: "memory");
            __builtin_amdgcn_s_barrier();
        }
        s  = (s  == 2) ? 0 : s  + 1;
        s2 = (s2 == 2) ? 0 : s2 + 1;
    }
#undef LDSA
#undef LDSB
#undef STAGE_A
#undef STAGE_B
}

// ---------------------------------------------------------------------------
// Fused q/k/v projection: 1152 blocks (256-row x 128-col tiles), r9 config.
//   bid <  768 : q = elu1(xq @ Wq.T)   (128 row-blocks x 6)
//   768..959   : k = elu1(xkv @ Wk.T)  ( 32 row-blocks x 6)
//   960..1151  : v =      xkv @ Wv.T
// ---------------------------------------------------------------------------
__global__ __launch_bounds__(512) void proj_qkv(
    const _Float16* __restrict__ xq16, const _Float16* __restrict__ xkv16,
    const _Float16* __restrict__ Wq16, const _Float16* __restrict__ Wk16,
    const _Float16* __restrict__ Wv16,
    _Float16* __restrict__ q16, _Float16* __restrict__ k16,
    _Float16* __restrict__ v16)
{
    __shared__ __align__(16) _Float16 lds[3 * 24576];   // 147456 B

    const int cpx = gridDim.x >> 3;                     // 1152/8 = 144
    int bid = (blockIdx.x & 7) * cpx + (blockIdx.x >> 3);

    const _Float16 *A, *W; _Float16* O; bool elu;
    int brow, bcol;
    if (bid < 768) {
        A = xq16; W = Wq16; O = q16; elu = true;
        brow = bid / 6; bcol = bid - brow * 6;
    } else {
        int u = bid - 768;
        int mat = u / 192;  u -= mat * 192;
        A = xkv16; W = mat ? Wv16 : Wk16; O = mat ? v16 : k16; elu = !mat;
        brow = u / 6; bcol = u - brow * 6;
    }
    const int row0 = brow * 256, col0 = bcol * 128;

    float4_t acc[8][2] = {};
    gemm_r4(A, W, row0, col0, lds, acc);

    const int wid = threadIdx.x >> 6, lane = threadIdx.x & 63;
    const int wr = wid >> 2, wc = wid & 3, lr = lane & 15, lkg = lane >> 4;
    #pragma unroll
    for (int mi = 0; mi < 8; ++mi) {
        #pragma unroll
        for (int ni = 0; ni < 2; ++ni) {
            #pragma unroll
            for (int e = 0; e < 4; ++e) {
                int r = row0 + wr * 128 + mi * 16 + lkg * 4 + e;
                int c = col0 + wc * 32 + ni * 16 + lr;
                float v = acc[mi][ni][e];
                if (elu) v = (v > 0.0f) ? (v + 1.0f) : __expf(v);  // elu(x)+1
                O[(size_t)r * DIM + c] = (_Float16)v;
            }
        }
    }
}

// ---------------------------------------------------------------------------
// out = attn16 @ Wo.T + bo  (fp32 output), 768 blocks — r9 config
// ---------------------------------------------------------------------------
__global__ __launch_bounds__(512) void out_proj(
    const _Float16* __restrict__ a16, const _Float16* __restrict__ Wo16,
    const float* __restrict__ bo, float* __restrict__ out)
{
    __shared__ __align__(16) _Float16 lds[3 * 24576];

    const int cpx = gridDim.x >> 3;                     // 768/8 = 96
    int bid = (blockIdx.x & 7) * cpx + (blockIdx.x >> 3);
    const int brow = bid / 6, bcol = bid - brow * 6;
    const int row0 = brow * 256, col0 = bcol * 128;

    float4_t acc[8][2] = {};
    gemm_r4(a16, Wo16, row0, col0, lds, acc);

    const int wid = threadIdx.x >> 6, lane = threadIdx.x & 63;
    const int wr = wid >> 2, wc = wid & 3, lr = lane & 15, lkg = lane >> 4;
    #pragma unroll
    for (int mi = 0; mi < 8; ++mi) {
        #pragma unroll
        for (int ni = 0; ni < 2; ++ni) {
            #pragma unroll
            for (int e = 0; e < 4; ++e) {
                int r = row0 + wr * 128 + mi * 16 + lkg * 4 + e;
                int c = col0 + wc * 32 + ni * 16 + lr;
                out[(size_t)r * DIM + c] = acc[mi][ni][e] + bo[c];
            }
        }
    }
}

// ---------------------------------------------------------------------------
// kv_reduce: per (b,h): kvh[e][d] = sum_n v[n,e]*k[n,d];  ksum[d] = sum_n k[n,d]
// ---------------------------------------------------------------------------
__global__ __launch_bounds__(256) void kv_reduce(const _Float16* __restrict__ k16,
                                                 const _Float16* __restrict__ v16,
                                                 float* __restrict__ kvh,
                                                 float* __restrict__ ksum)
{
    __shared__ __align__(16) _Float16 K[128][64];
    __shared__ __align__(16) _Float16 V[128][64];
    const int chunk = blockIdx.x;   // 0..7
    const int bh    = blockIdx.y;   // 0..95
    const int b = bh / 12, h = bh % 12;
    const int tid = threadIdx.x;

    const size_t base = ((size_t)b * 1024 + (size_t)chunk * 128) * DIM + h * 64;
    #pragma unroll
    for (int j = 0; j < 4; ++j) {
        int idx = j * 256 + tid;
        int r = idx >> 3, c = (idx & 7) * 8;
        *(half8_t*)&K[r][c] = *(const half8_t*)&k16[base + (size_t)r * DIM + c];
        *(half8_t*)&V[r][c] = *(const half8_t*)&v16[base + (size_t)r * DIM + c];
    }
    __syncthreads();

    const int d0 = (tid & 15) * 4;
    const int e0 = (tid >> 4) * 4;
    float acc[4][4] = {};
    #pragma unroll 4
    for (int n = 0; n < 128; ++n) {
        half4_t kd = *(const half4_t*)&K[n][d0];
        half4_t ve = *(const half4_t*)&V[n][e0];
        #pragma unroll
        for (int i = 0; i < 4; ++i)
            #pragma unroll
            for (int j = 0; j < 4; ++j)
                acc[i][j] += (float)ve[i] * (float)kd[j];
    }
    float* kvp = kvh + (size_t)bh * 64 * 64;
    #pragma unroll
    for (int i = 0; i < 4; ++i)
        #pragma unroll
        for (int j = 0; j < 4; ++j)
            atomicAdd(&kvp[(e0 + i) * 64 + d0 + j], acc[i][j]);

    if (tid < 64) {
        float s = 0.0f;
        for (int n = 0; n < 128; ++n) s += (float)K[n][tid];
        atomicAdd(&ksum[bh * 64 + tid], s);
    }
}

// ---------------------------------------------------------------------------
// attn: z = 1/(q . ksum + 1e-6); attn = (q @ kv) * z   (in-place on q16)
// ---------------------------------------------------------------------------
__global__ __launch_bounds__(256) void attn_kernel(_Float16* __restrict__ q16,
                                                   const float* __restrict__ kvh,
                                                   const float* __restrict__ ksum)
{
    __shared__ __align__(16) _Float16 Q[128][72];
    __shared__ __align__(16) _Float16 Bv[64][72];
    __shared__ float S[64];
    __shared__ float Z[128];

    const int h    = blockIdx.x;        // 0..11
    const int rb   = blockIdx.y;        // 0..255
    const int row0 = rb * 128;
    const int b    = row0 >> 12;
    const int bh   = b * 12 + h;
    const int tid  = threadIdx.x;

    #pragma unroll
    for (int j = 0; j < 4; ++j) {
        int idx = j * 256 + tid;
        int r = idx >> 3, c = (idx & 7) * 8;
        *(half8_t*)&Q[r][c] =
            *(const half8_t*)&q16[(size_t)(row0 + r) * DIM + h * 64 + c];
    }
    #pragma unroll
    for (int j = 0; j < 4; ++j) {
        int idx = j * 256 + tid;
        int r = idx >> 4, c = (idx & 15) * 4;
        float4_t f = *(const float4_t*)&kvh[((size_t)bh * 64 + r) * 64 + c];
        half4_t hh;
        #pragma unroll
        for (int e = 0; e < 4; ++e) hh[e] = (_Float16)f[e];
        *(half4_t*)&Bv[r][c] = hh;
    }
    if (tid < 64) S[tid] = ksum[bh * 64 + tid];
    __syncthreads();

    if (tid < 128) {
        float dot = 0.0f;
        #pragma unroll 8
        for (int d = 0; d < 64; ++d) dot += (float)Q[tid][d] * S[d];
        Z[tid] = 1.0f / (dot + 1e-6f);
    }
    __syncthreads();

    const int w = tid >> 6, lane = tid & 63;
    const int lr = lane & 15, lkg = lane >> 4;
    float4_t acc[2][4] = {};
    #pragma unroll
    for (int kc = 0; kc < 2; ++kc) {
        half8_t aF[2], bF[4];
        #pragma unroll
        for (int mi = 0; mi < 2; ++mi)
            aF[mi] = *(const half8_t*)&Q[w * 32 + mi * 16 + lr][kc * 32 + lkg * 8];
        #pragma unroll
        for (int ni = 0; ni < 4; ++ni)
            bF[ni] = *(const half8_t*)&Bv[ni * 16 + lr][kc * 32 + lkg * 8];
        #pragma unroll
        for (int mi = 0; mi < 2; ++mi)
            #pragma unroll
            for (int ni = 0; ni < 4; ++ni)
                acc[mi][ni] = MFMA16(aF[mi], bF[ni], acc[mi][ni]);
    }
    #pragma unroll
    for (int mi = 0; mi < 2; ++mi) {
        #pragma unroll
        for (int ni = 0; ni < 4; ++ni) {
            #pragma unroll
            for (int e = 0; e < 4; ++e) {
                int r = w * 32 + mi * 16 + lkg * 4 + e;
                float v = acc[mi][ni][e] * Z[r];
                q16[(size_t)(row0 + r) * DIM + h * 64 + ni * 16 + lr] = (_Float16)v;
            }
        }
    }
}

// ---------------------------------------------------------------------------
extern "C" void kernel_launch(void* const* d_in, const int* in_sizes, int n_in,
                              void* d_out, int out_size, void* d_ws, size_t ws_size,
                              hipStream_t stream)
{
    const float* xq  = (const float*)d_in[0];  // [8,4096,768]
    const float* xkv = (const float*)d_in[1];  // [8,1024,768]
    const float* Wq  = (const float*)d_in[2];
    const float* Wk  = (const float*)d_in[3];
    const float* Wv  = (const float*)d_in[4];
    const float* Wo  = (const float*)d_in[5];
    const float* bo  = (const float*)d_in[6];

    // ---- workspace layout (~69 MB) ----
    char* ws = (char*)d_ws;
    const size_t SZ_Q16   = (size_t)32768 * 768 * 2;   // 50,331,648
    const size_t SZ_XKV16 = (size_t)8192 * 768 * 2;    // 12,582,912
    const size_t SZ_W16   = (size_t)768 * 768 * 2;     //  1,179,648
    const size_t SZ_KVH   = (size_t)96 * 64 * 64 * 4;  //  1,572,864
    const size_t SZ_KSUM  = (size_t)96 * 64 * 4;       //     24,576

    _Float16* q16   = (_Float16*)(ws);
    _Float16* xkv16 = (_Float16*)(ws + SZ_Q16);
    _Float16* Wq16  = (_Float16*)(ws + SZ_Q16 + SZ_XKV16);            // 4 contiguous
    _Float16* Wk16  = (_Float16*)(ws + SZ_Q16 + SZ_XKV16 + SZ_W16);
    _Float16* Wv16  = (_Float16*)(ws + SZ_Q16 + SZ_XKV16 + 2 * SZ_W16);
    _Float16* Wo16  = (_Float16*)(ws + SZ_Q16 + SZ_XKV16 + 3 * SZ_W16);
    float*    kvh   = (float*)   (ws + SZ_Q16 + SZ_XKV16 + 4 * SZ_W16);
    float*    ksum  = (float*)   (ws + SZ_Q16 + SZ_XKV16 + 4 * SZ_W16 + SZ_KVH);

    // ---- d_out aliasing: xq16 consumed by proj_qkv; k16/v16 by kv_reduce;
    //      all dead before out_proj overwrites d_out. ----
    char* ob = (char*)d_out;
    _Float16* xq16 = (_Float16*)(ob);                       // 50,331,648
    _Float16* k16  = (_Float16*)(ob + 50331648);            // 12,582,912
    _Float16* v16  = (_Float16*)(ob + 50331648 + 12582912); // 12,582,912
    float*    out  = (float*)d_out;

    // 1) one fused cast + zero launch (memset folded in)
    cast_all<<<16902, 256, 0, stream>>>(xq, xkv, Wq, Wk, Wv, Wo,
                                        xq16, xkv16, Wq16, kvh);

    // 2) fused projections: q = elu1(xq@Wq.T), k = elu1(xkv@Wk.T), v = xkv@Wv.T
    proj_qkv<<<1152, 512, 0, stream>>>(xq16, xkv16, Wq16, Wk16, Wv16,
                                       q16, k16, v16);

    // 3) linear attention
    kv_reduce<<<dim3(8, 96), 256, 0, stream>>>(k16, v16, kvh, ksum);
    attn_kernel<<<dim3(12, 256), 256, 0, stream>>>(q16, kvh, ksum);

    // 4) out = attn @ Wo.T + bo  (fp32 output)
    out_proj<<<768, 512, 0, stream>>>(q16, Wo16, bo, out);
}

// Round 14
// 218.461 us; speedup vs baseline: 1.1695x; 1.0157x over previous
//
#include <hip/hip_runtime.h>

typedef _Float16 half8_t __attribute__((ext_vector_type(8)));
typedef _Float16 half4_t __attribute__((ext_vector_type(4)));
typedef float    float4_t __attribute__((ext_vector_type(4)));

#define DIM 768

// async global->LDS, 16B per lane; LDS dest is wave-uniform base + lane*16
#define GLOAD16(g, l) __builtin_amdgcn_global_load_lds(                        \
    (const __attribute__((address_space(1))) void*)(g),                        \
    (__attribute__((address_space(3))) void*)(l), 16, 0, 0)

#define MFMA16(a, b, c) __builtin_amdgcn_mfma_f32_16x16x32_f16((a), (b), (c), 0, 0, 0)

// ---------------------------------------------------------------------------
// one fused cast launch: xq | xkv | weights | zero kvh+ksum (memset folded)
// ---------------------------------------------------------------------------
__global__ __launch_bounds__(256) void cast_all(
    const float* __restrict__ xq,  const float* __restrict__ xkv,
    const float* __restrict__ Wq,  const float* __restrict__ Wk,
    const float* __restrict__ Wv,  const float* __restrict__ Wo,
    _Float16* __restrict__ dq, _Float16* __restrict__ dkv,
    _Float16* __restrict__ dW /* 4 matrices contiguous */,
    float* __restrict__ kvz /* kvh+ksum region, 399,360 floats */)
{
    int i = blockIdx.x * 256 + threadIdx.x;
    if (i >= 4227072) {                        // zero kvh/ksum tail
        int z = i - 4227072;
        if (z < 99840) {
            float4_t zf = {0.f, 0.f, 0.f, 0.f};
            *(float4_t*)&kvz[(size_t)z * 4] = zf;
        }
        return;
    }
    const float* s; _Float16* d; int off;
    if (i < 3145728)      { s = xq;  d = dq;  off = i; }
    else if (i < 3932160) { s = xkv; d = dkv; off = i - 3145728; }
    else {
        int j = i - 3932160;                   // 0..294911
        int w = j / 73728;  off = j - w * 73728;
        s = (w == 0) ? Wq : (w == 1) ? Wk : (w == 2) ? Wv : Wo;
        d = dW + (size_t)w * 589824;
    }
    float4_t f0 = *(const float4_t*)&s[(size_t)off * 8];
    float4_t f1 = *(const float4_t*)&s[(size_t)off * 8 + 4];
    half8_t h;
    #pragma unroll
    for (int e = 0; e < 4; ++e) { h[e] = (_Float16)f0[e]; h[e + 4] = (_Float16)f1[e]; }
    *(half8_t*)&d[(size_t)off * 8] = h;
}

// ---------------------------------------------------------------------------
// Shared setup for both cores: 256x128 tile, BK=64, 8 waves, 3 slots of 48KB,
// XOR-granule swizzle (inverse-swizzled global src + swizzled ds_read),
// stage tile t+2 while computing t, counted vmcnt(6) never 0 until tail.
// ---------------------------------------------------------------------------
#define GEMM_SETUP                                                             \
    const int tid  = threadIdx.x;                                              \
    const int wid  = tid >> 6, lane = tid & 63;                                \
    const int wr   = wid >> 2;                                                 \
    const int wc   = wid & 3;                                                  \
    const int lr   = lane & 15;                                                \
    const int lkg  = lane >> 4;                                                \
    const int x    = lr & 7;                                                   \
    const int  srow = wid * 8 + (lane >> 3);                                   \
    const int  sg   = ((lane & 7) ^ (lane >> 3)) * 8;                          \
    const _Float16* Ast = A + (size_t)(row0 + srow) * DIM + sg;                \
    const _Float16* Bst = W + (size_t)(col0 + srow) * DIM + sg;                \
    const int ard = (wr * 128 + lr) * 64;                                      \
    const int brd = (wc * 32 + lr) * 64;                                       \
    const int g0  = (lkg ^ x) * 8;                                             \
    const int g1  = g0 ^ 32;

#define LDSA(s) (&lds[(s) * 24576])
#define LDSB(s) (&lds[(s) * 24576 + 16384])
#define STAGE_A(t, s, j) GLOAD16(Ast + (size_t)(t) * 64 + (size_t)(j) * 64 * DIM, \
                                 LDSA(s) + (j) * 4096 + wid * 512)
#define STAGE_B(t, s, j) GLOAD16(Bst + (size_t)(t) * 64 + (size_t)(j) * 64 * DIM, \
                                 LDSB(s) + (j) * 4096 + wid * 512)

// ---------------------------------------------------------------------------
// gemm_1b — EXPERIMENT: r4 geometry/staging/vmcnt verbatim, but ONE barrier
// per tile. Hazard audit: (a) STAGE into s2 is issued only after the tile-t
// start barrier; slot s2 was last read during tile t-1, and every wave's
// ds_reads completed at its own lgkmcnt(0) before its MFMAs, which precede
// that barrier -> no read-overwrite race. (b) boundary vmcnt(6) leaves only
// tile-(t+2) loads outstanding -> tile t+1 fully landed before its reads.
// The two mid-tile barriers of r4 protected nothing; this is a clean A/B.
// ---------------------------------------------------------------------------
__device__ __forceinline__ void gemm_1b(const _Float16* __restrict__ A,
                                        const _Float16* __restrict__ W,
                                        int row0, int col0,
                                        _Float16* lds, float4_t acc[8][2])
{
    GEMM_SETUP

    STAGE_A(0, 0, 0); STAGE_A(0, 0, 1); STAGE_A(0, 0, 2); STAGE_A(0, 0, 3);
    STAGE_B(0, 0, 0); STAGE_B(0, 0, 1);
    STAGE_A(1, 1, 0); STAGE_A(1, 1, 1); STAGE_A(1, 1, 2); STAGE_A(1, 1, 3);
    STAGE_B(1, 1, 0); STAGE_B(1, 1, 1);
    asm volatile("s_waitcnt vmcnt(6)" ::: "memory");
    __builtin_amdgcn_s_barrier();
    __builtin_amdgcn_sched_barrier(0);

    int s = 0, s2 = 2;
    for (int t = 0; t < 12; ++t) {
        const _Float16* Asl = LDSA(s);
        const _Float16* Bsl = LDSB(s);
        const bool pf = (t < 10);

        half8_t bf[2][2], af[8][2];
        bf[0][0] = *(const half8_t*)&Bsl[brd + g0];
        bf[0][1] = *(const half8_t*)&Bsl[brd + g1];
        bf[1][0] = *(const half8_t*)&Bsl[brd + 1024 + g0];
        bf[1][1] = *(const half8_t*)&Bsl[brd + 1024 + g1];
        #pragma unroll
        for (int i = 0; i < 8; ++i) {
            af[i][0] = *(const half8_t*)&Asl[ard + i * 1024 + g0];
            af[i][1] = *(const half8_t*)&Asl[ard + i * 1024 + g1];
        }
        if (pf) {
            STAGE_A(t + 2, s2, 0); STAGE_A(t + 2, s2, 1);
            STAGE_A(t + 2, s2, 2); STAGE_A(t + 2, s2, 3);
            STAGE_B(t + 2, s2, 0); STAGE_B(t + 2, s2, 1);
        }

        asm volatile("s_waitcnt lgkmcnt(0)" ::: "memory");
        __builtin_amdgcn_sched_barrier(0);
        __builtin_amdgcn_s_setprio(1);
        #pragma unroll
        for (int i = 0; i < 8; ++i)
            #pragma unroll
            for (int ni = 0; ni < 2; ++ni) {
                acc[i][ni] = MFMA16(af[i][0], bf[ni][0], acc[i][ni]);
                acc[i][ni] = MFMA16(af[i][1], bf[ni][1], acc[i][ni]);
            }
        __builtin_amdgcn_s_setprio(0);
        __builtin_amdgcn_sched_barrier(0);

        if (t < 11) {
            if (pf) asm volatile("s_waitcnt vmcnt(6)" ::: "memory");
            else    asm volatile("s_waitcnt vmcnt(0)" ::: "memory");
            __builtin_amdgcn_s_barrier();
            __builtin_amdgcn_sched_barrier(0);
        }
        s  = (s  == 2) ? 0 : s  + 1;
        s2 = (s2 == 2) ? 0 : s2 + 1;
    }
}

// ---------------------------------------------------------------------------
// gemm_r4 — measured-best core (r4/r9/r13 verbatim; CONTROL for out_proj)
// ---------------------------------------------------------------------------
__device__ __forceinline__ void gemm_r4(const _Float16* __restrict__ A,
                                        const _Float16* __restrict__ W,
                                        int row0, int col0,
                                        _Float16* lds, float4_t acc[8][2])
{
    GEMM_SETUP

    STAGE_A(0, 0, 0); STAGE_A(0, 0, 1); STAGE_A(0, 0, 2); STAGE_A(0, 0, 3);
    STAGE_B(0, 0, 0); STAGE_B(0, 0, 1);
    STAGE_A(1, 1, 0); STAGE_A(1, 1, 1); STAGE_A(1, 1, 2); STAGE_A(1, 1, 3);
    STAGE_B(1, 1, 0); STAGE_B(1, 1, 1);
    asm volatile("s_waitcnt vmcnt(6)" ::: "memory");
    __builtin_amdgcn_s_barrier();

    int s = 0, s2 = 2;
    for (int t = 0; t < 12; ++t) {
        const _Float16* Asl = LDSA(s);
        const _Float16* Bsl = LDSB(s);
        const bool pf = (t < 10);

        // ================= phase 0 : mi 0..3 =================
        half8_t bf[2][2];
        bf[0][0] = *(const half8_t*)&Bsl[brd + g0];
        bf[0][1] = *(const half8_t*)&Bsl[brd + g1];
        bf[1][0] = *(const half8_t*)&Bsl[brd + 1024 + g0];
        bf[1][1] = *(const half8_t*)&Bsl[brd + 1024 + g1];
        half8_t af0[4][2];
        #pragma unroll
        for (int i = 0; i < 4; ++i) {
            af0[i][0] = *(const half8_t*)&Asl[ard + i * 1024 + g0];
            af0[i][1] = *(const half8_t*)&Asl[ard + i * 1024 + g1];
        }
        if (pf) { STAGE_A(t + 2, s2, 0); STAGE_A(t + 2, s2, 1); STAGE_A(t + 2, s2, 2); }
        __builtin_amdgcn_s_barrier();
        asm volatile("s_waitcnt lgkmcnt(0)" ::: "memory");
        __builtin_amdgcn_sched_barrier(0);
        __builtin_amdgcn_s_setprio(1);
        #pragma unroll
        for (int i = 0; i < 4; ++i)
            #pragma unroll
            for (int ni = 0; ni < 2; ++ni) {
                acc[i][ni] = MFMA16(af0[i][0], bf[ni][0], acc[i][ni]);
                acc[i][ni] = MFMA16(af0[i][1], bf[ni][1], acc[i][ni]);
            }
        __builtin_amdgcn_s_setprio(0);
        __builtin_amdgcn_sched_barrier(0);
        __builtin_amdgcn_s_barrier();

        // ================= phase 1 : mi 4..7 =================
        half8_t af1[4][2];
        #pragma unroll
        for (int i = 0; i < 4; ++i) {
            af1[i][0] = *(const half8_t*)&Asl[ard + 4096 + i * 1024 + g0];
            af1[i][1] = *(const half8_t*)&Asl[ard + 4096 + i * 1024 + g1];
        }
        if (pf) { STAGE_A(t + 2, s2, 3); STAGE_B(t + 2, s2, 0); STAGE_B(t + 2, s2, 1); }
        __builtin_amdgcn_s_barrier();
        asm volatile("s_waitcnt lgkmcnt(0)" ::: "memory");
        __builtin_amdgcn_sched_barrier(0);
        __builtin_amdgcn_s_setprio(1);
        #pragma unroll
        for (int i = 0; i < 4; ++i)
            #pragma unroll
            for (int ni = 0; ni < 2; ++ni) {
                acc[4 + i][ni] = MFMA16(af1[i][0], bf[ni][0], acc[4 + i][ni]);
                acc[4 + i][ni] = MFMA16(af1[i][1], bf[ni][1], acc[4 + i][ni]);
            }
        __builtin_amdgcn_s_setprio(0);
        __builtin_amdgcn_sched_barrier(0);

        if (t < 11) {
            if (pf) asm volatile("s_waitcnt vmcnt(6)" ::: "memory");
            else    asm volatile("s_waitcnt vmcnt(0)" ::: "memory");
            __builtin_amdgcn_s_barrier();
        }
        s  = (s  == 2) ? 0 : s  + 1;
        s2 = (s2 == 2) ? 0 : s2 + 1;
    }
}

// ---------------------------------------------------------------------------
// Fused q/k/v projection: 1152 blocks (256x128 tiles) — gemm_1b experiment
// ---------------------------------------------------------------------------
__global__ __launch_bounds__(512) void proj_qkv(
    const _Float16* __restrict__ xq16, const _Float16* __restrict__ xkv16,
    const _Float16* __restrict__ Wq16, const _Float16* __restrict__ Wk16,
    const _Float16* __restrict__ Wv16,
    _Float16* __restrict__ q16, _Float16* __restrict__ k16,
    _Float16* __restrict__ v16)
{
    __shared__ __align__(16) _Float16 lds[3 * 24576];   // 147456 B

    const int cpx = gridDim.x >> 3;                     // 1152/8 = 144
    int bid = (blockIdx.x & 7) * cpx + (blockIdx.x >> 3);

    const _Float16 *A, *W; _Float16* O; bool elu;
    int brow, bcol;
    if (bid < 768) {
        A = xq16; W = Wq16; O = q16; elu = true;
        brow = bid / 6; bcol = bid - brow * 6;
    } else {
        int u = bid - 768;
        int mat = u / 192;  u -= mat * 192;
        A = xkv16; W = mat ? Wv16 : Wk16; O = mat ? v16 : k16; elu = !mat;
        brow = u / 6; bcol = u - brow * 6;
    }
    const int row0 = brow * 256, col0 = bcol * 128;

    float4_t acc[8][2] = {};
    gemm_1b(A, W, row0, col0, lds, acc);

    const int wid = threadIdx.x >> 6, lane = threadIdx.x & 63;
    const int wr = wid >> 2, wc = wid & 3, lr = lane & 15, lkg = lane >> 4;
    #pragma unroll
    for (int mi = 0; mi < 8; ++mi) {
        #pragma unroll
        for (int ni = 0; ni < 2; ++ni) {
            #pragma unroll
            for (int e = 0; e < 4; ++e) {
                int r = row0 + wr * 128 + mi * 16 + lkg * 4 + e;
                int c = col0 + wc * 32 + ni * 16 + lr;
                float v = acc[mi][ni][e];
                if (elu) v = (v > 0.0f) ? (v + 1.0f) : __expf(v);  // elu(x)+1
                O[(size_t)r * DIM + c] = (_Float16)v;
            }
        }
    }
}

// ---------------------------------------------------------------------------
// out = attn16 @ Wo.T + bo  (fp32 output), 768 blocks — gemm_r4 CONTROL
// ---------------------------------------------------------------------------
__global__ __launch_bounds__(512) void out_proj(
    const _Float16* __restrict__ a16, const _Float16* __restrict__ Wo16,
    const float* __restrict__ bo, float* __restrict__ out)
{
    __shared__ __align__(16) _Float16 lds[3 * 24576];

    const int cpx = gridDim.x >> 3;                     // 768/8 = 96
    int bid = (blockIdx.x & 7) * cpx + (blockIdx.x >> 3);
    const int brow = bid / 6, bcol = bid - brow * 6;
    const int row0 = brow * 256, col0 = bcol * 128;

    float4_t acc[8][2] = {};
    gemm_r4(a16, Wo16, row0, col0, lds, acc);

    const int wid = threadIdx.x >> 6, lane = threadIdx.x & 63;
    const int wr = wid >> 2, wc = wid & 3, lr = lane & 15, lkg = lane >> 4;
    #pragma unroll
    for (int mi = 0; mi < 8; ++mi) {
        #pragma unroll
        for (int ni = 0; ni < 2; ++ni) {
            #pragma unroll
            for (int e = 0; e < 4; ++e) {
                int r = row0 + wr * 128 + mi * 16 + lkg * 4 + e;
                int c = col0 + wc * 32 + ni * 16 + lr;
                out[(size_t)r * DIM + c] = acc[mi][ni][e] + bo[c];
            }
        }
    }
}

// ---------------------------------------------------------------------------
// kv_reduce: per (b,h): kvh[e][d] = sum_n v[n,e]*k[n,d];  ksum[d] = sum_n k[n,d]
// ---------------------------------------------------------------------------
__global__ __launch_bounds__(256) void kv_reduce(const _Float16* __restrict__ k16,
                                                 const _Float16* __restrict__ v16,
                                                 float* __restrict__ kvh,
                                                 float* __restrict__ ksum)
{
    __shared__ __align__(16) _Float16 K[128][64];
    __shared__ __align__(16) _Float16 V[128][64];
    const int chunk = blockIdx.x;   // 0..7
    const int bh    = blockIdx.y;   // 0..95
    const int b = bh / 12, h = bh % 12;
    const int tid = threadIdx.x;

    const size_t base = ((size_t)b * 1024 + (size_t)chunk * 128) * DIM + h * 64;
    #pragma unroll
    for (int j = 0; j < 4; ++j) {
        int idx = j * 256 + tid;
        int r = idx >> 3, c = (idx & 7) * 8;
        *(half8_t*)&K[r][c] = *(const half8_t*)&k16[base + (size_t)r * DIM + c];
        *(half8_t*)&V[r][c] = *(const half8_t*)&v16[base + (size_t)r * DIM + c];
    }
    __syncthreads();

    const int d0 = (tid & 15) * 4;
    const int e0 = (tid >> 4) * 4;
    float acc[4][4] = {};
    #pragma unroll 4
    for (int n = 0; n < 128; ++n) {
        half4_t kd = *(const half4_t*)&K[n][d0];
        half4_t ve = *(const half4_t*)&V[n][e0];
        #pragma unroll
        for (int i = 0; i < 4; ++i)
            #pragma unroll
            for (int j = 0; j < 4; ++j)
                acc[i][j] += (float)ve[i] * (float)kd[j];
    }
    float* kvp = kvh + (size_t)bh * 64 * 64;
    #pragma unroll
    for (int i = 0; i < 4; ++i)
        #pragma unroll
        for (int j = 0; j < 4; ++j)
            atomicAdd(&kvp[(e0 + i) * 64 + d0 + j], acc[i][j]);

    if (tid < 64) {
        float s = 0.0f;
        for (int n = 0; n < 128; ++n) s += (float)K[n][tid];
        atomicAdd(&ksum[bh * 64 + tid], s);
    }
}

// ---------------------------------------------------------------------------
// attn: z = 1/(q . ksum + 1e-6); attn = (q @ kv) * z   (in-place on q16)
// ---------------------------------------------------------------------------
__global__ __launch_bounds__(256) void attn_kernel(_Float16* __restrict__ q16,
                                                   const float* __restrict__ kvh,
                                                   const float* __restrict__ ksum)
{
    __shared__ __align__(16) _Float16 Q[128][72];
    __shared__ __align__(16) _Float16 Bv[64][72];
    __shared__ float S[64];
    __shared__ float Z[128];

    const int h    = blockIdx.x;        // 0..11
    const int rb   = blockIdx.y;        // 0..255
    const int row0 = rb * 128;
    const int b    = row0 >> 12;
    const int bh   = b * 12 + h;
    const int tid  = threadIdx.x;

    #pragma unroll
    for (int j = 0; j < 4; ++j) {
        int idx = j * 256 + tid;
        int r = idx >> 3, c = (idx & 7) * 8;
        *(half8_t*)&Q[r][c] =
            *(const half8_t*)&q16[(size_t)(row0 + r) * DIM + h * 64 + c];
    }
    #pragma unroll
    for (int j = 0; j < 4; ++j) {
        int idx = j * 256 + tid;
        int r = idx >> 4, c = (idx & 15) * 4;
        float4_t f = *(const float4_t*)&kvh[((size_t)bh * 64 + r) * 64 + c];
        half4_t hh;
        #pragma unroll
        for (int e = 0; e < 4; ++e) hh[e] = (_Float16)f[e];
        *(half4_t*)&Bv[r][c] = hh;
    }
    if (tid < 64) S[tid] = ksum[bh * 64 + tid];
    __syncthreads();

    if (tid < 128) {
        float dot = 0.0f;
        #pragma unroll 8
        for (int d = 0; d < 64; ++d) dot += (float)Q[tid][d] * S[d];
        Z[tid] = 1.0f / (dot + 1e-6f);
    }
    __syncthreads();

    const int w = tid >> 6, lane = tid & 63;
    const int lr = lane & 15, lkg = lane >> 4;
    float4_t acc[2][4] = {};
    #pragma unroll
    for (int kc = 0; kc < 2; ++kc) {
        half8_t aF[2], bF[4];
        #pragma unroll
        for (int mi = 0; mi < 2; ++mi)
            aF[mi] = *(const half8_t*)&Q[w * 32 + mi * 16 + lr][kc * 32 + lkg * 8];
        #pragma unroll
        for (int ni = 0; ni < 4; ++ni)
            bF[ni] = *(const half8_t*)&Bv[ni * 16 + lr][kc * 32 + lkg * 8];
        #pragma unroll
        for (int mi = 0; mi < 2; ++mi)
            #pragma unroll
            for (int ni = 0; ni < 4; ++ni)
                acc[mi][ni] = MFMA16(aF[mi], bF[ni], acc[mi][ni]);
    }
    #pragma unroll
    for (int mi = 0; mi < 2; ++mi) {
        #pragma unroll
        for (int ni = 0; ni < 4; ++ni) {
            #pragma unroll
            for (int e = 0; e < 4; ++e) {
                int r = w * 32 + mi * 16 + lkg * 4 + e;
                float v = acc[mi][ni][e] * Z[r];
                q16[(size_t)(row0 + r) * DIM + h * 64 + ni * 16 + lr] = (_Float16)v;
            }
        }
    }
}

// ---------------------------------------------------------------------------
extern "C" void kernel_launch(void* const* d_in, const int* in_sizes, int n_in,
                              void* d_out, int out_size, void* d_ws, size_t ws_size,
                              hipStream_t stream)
{
    const float* xq  = (const float*)d_in[0];  // [8,4096,768]
    const float* xkv = (const float*)d_in[1];  // [8,1024,768]
    const float* Wq  = (const float*)d_in[2];
    const float* Wk  = (const float*)d_in[3];
    const float* Wv  = (const float*)d_in[4];
    const float* Wo  = (const float*)d_in[5];
    const float* bo  = (const float*)d_in[6];

    // ---- workspace layout (~69 MB) ----
    char* ws = (char*)d_ws;
    const size_t SZ_Q16   = (size_t)32768 * 768 * 2;   // 50,331,648
    const size_t SZ_XKV16 = (size_t)8192 * 768 * 2;    // 12,582,912
    const size_t SZ_W16   = (size_t)768 * 768 * 2;     //  1,179,648
    const size_t SZ_KVH   = (size_t)96 * 64 * 64 * 4;  //  1,572,864
    const size_t SZ_KSUM  = (size_t)96 * 64 * 4;       //     24,576

    _Float16* q16   = (_Float16*)(ws);
    _Float16* xkv16 = (_Float16*)(ws + SZ_Q16);
    _Float16* Wq16  = (_Float16*)(ws + SZ_Q16 + SZ_XKV16);            // 4 contiguous
    _Float16* Wk16  = (_Float16*)(ws + SZ_Q16 + SZ_XKV16 + SZ_W16);
    _Float16* Wv16  = (_Float16*)(ws + SZ_Q16 + SZ_XKV16 + 2 * SZ_W16);
    _Float16* Wo16  = (_Float16*)(ws + SZ_Q16 + SZ_XKV16 + 3 * SZ_W16);
    float*    kvh   = (float*)   (ws + SZ_Q16 + SZ_XKV16 + 4 * SZ_W16);
    float*    ksum  = (float*)   (ws + SZ_Q16 + SZ_XKV16 + 4 * SZ_W16 + SZ_KVH);

    // ---- d_out aliasing: xq16 consumed by proj_qkv; k16/v16 by kv_reduce;
    //      all dead before out_proj overwrites d_out. ----
    char* ob = (char*)d_out;
    _Float16* xq16 = (_Float16*)(ob);                       // 50,331,648
    _Float16* k16  = (_Float16*)(ob + 50331648);            // 12,582,912
    _Float16* v16  = (_Float16*)(ob + 50331648 + 12582912); // 12,582,912
    float*    out  = (float*)d_out;

    // 1) one fused cast + zero launch
    cast_all<<<16902, 256, 0, stream>>>(xq, xkv, Wq, Wk, Wv, Wo,
                                        xq16, xkv16, Wq16, kvh);

    // 2) fused projections: q = elu1(xq@Wq.T), k = elu1(xkv@Wk.T), v = xkv@Wv.T
    proj_qkv<<<1152, 512, 0, stream>>>(xq16, xkv16, Wq16, Wk16, Wv16,
                                       q16, k16, v16);

    // 3) linear attention
    kv_reduce<<<dim3(8, 96), 256, 0, stream>>>(k16, v16, kvh, ksum);
    attn_kernel<<<dim3(12, 256), 256, 0, stream>>>(q16, kvh, ksum);

    // 4) out = attn @ Wo.T + bo  (fp32 output)
    out_proj<<<768, 512, 0, stream>>>(q16, Wo16, bo, out);
}

// Round 15
// 216.393 us; speedup vs baseline: 1.1806x; 1.0096x over previous
//
#include <hip/hip_runtime.h>

typedef _Float16 half8_t __attribute__((ext_vector_type(8)));
typedef _Float16 half4_t __attribute__((ext_vector_type(4)));
typedef float    float4_t __attribute__((ext_vector_type(4)));

#define DIM 768

// async global->LDS, 16B per lane; LDS dest is wave-uniform base + lane*16
#define GLOAD16(g, l) __builtin_amdgcn_global_load_lds(                        \
    (const __attribute__((address_space(1))) void*)(g),                        \
    (__attribute__((address_space(3))) void*)(l), 16, 0, 0)

#define MFMA16(a, b, c) __builtin_amdgcn_mfma_f32_16x16x32_f16((a), (b), (c), 0, 0, 0)

// ---------------------------------------------------------------------------
// one fused cast launch: xq | xkv | weights | zero kvh+ksum (memset folded)
// ---------------------------------------------------------------------------
__global__ __launch_bounds__(256) void cast_all(
    const float* __restrict__ xq,  const float* __restrict__ xkv,
    const float* __restrict__ Wq,  const float* __restrict__ Wk,
    const float* __restrict__ Wv,  const float* __restrict__ Wo,
    _Float16* __restrict__ dq, _Float16* __restrict__ dkv,
    _Float16* __restrict__ dW /* 4 matrices contiguous */,
    float* __restrict__ kvz /* kvh+ksum region, 399,360 floats */)
{
    int i = blockIdx.x * 256 + threadIdx.x;
    if (i >= 4227072) {                        // zero kvh/ksum tail
        int z = i - 4227072;
        if (z < 99840) {
            float4_t zf = {0.f, 0.f, 0.f, 0.f};
            *(float4_t*)&kvz[(size_t)z * 4] = zf;
        }
        return;
    }
    const float* s; _Float16* d; int off;
    if (i < 3145728)      { s = xq;  d = dq;  off = i; }
    else if (i < 3932160) { s = xkv; d = dkv; off = i - 3145728; }
    else {
        int j = i - 3932160;                   // 0..294911
        int w = j / 73728;  off = j - w * 73728;
        s = (w == 0) ? Wq : (w == 1) ? Wk : (w == 2) ? Wv : Wo;
        d = dW + (size_t)w * 589824;
    }
    float4_t f0 = *(const float4_t*)&s[(size_t)off * 8];
    float4_t f1 = *(const float4_t*)&s[(size_t)off * 8 + 4];
    half8_t h;
    #pragma unroll
    for (int e = 0; e < 4; ++e) { h[e] = (_Float16)f0[e]; h[e + 4] = (_Float16)f1[e]; }
    *(half8_t*)&d[(size_t)off * 8] = h;
}

// ---------------------------------------------------------------------------
// gemm_1b — measured-best core (r14 WIN: 96.3µs proj vs 103.5 for 4-barrier):
// 256x128 tile, BK=64, 512 thr = 8 waves (2M x 4N), per-wave C 128x32.
// 3 LDS slots (48KB each), XOR-granule swizzle (0 conflicts), stage tile t+2
// while computing t, counted vmcnt(6) never 0 until tail, ONE barrier/tile.
// Hazards: (a) STAGE into s2 issued after tile-t start barrier; slot s2 last
// read during tile t-1, and every wave's ds_reads completed at its own
// lgkmcnt(0) before its MFMAs, which precede that barrier. (b) boundary
// vmcnt(6) leaves only tile-(t+2) loads outstanding -> t+1 fully landed.
// ---------------------------------------------------------------------------
#define GEMM_SETUP                                                             \
    const int tid  = threadIdx.x;                                              \
    const int wid  = tid >> 6, lane = tid & 63;                                \
    const int wr   = wid >> 2;                                                 \
    const int wc   = wid & 3;                                                  \
    const int lr   = lane & 15;                                                \
    const int lkg  = lane >> 4;                                                \
    const int x    = lr & 7;                                                   \
    const int  srow = wid * 8 + (lane >> 3);                                   \
    const int  sg   = ((lane & 7) ^ (lane >> 3)) * 8;                          \
    const _Float16* Ast = A + (size_t)(row0 + srow) * DIM + sg;                \
    const _Float16* Bst = W + (size_t)(col0 + srow) * DIM + sg;                \
    const int ard = (wr * 128 + lr) * 64;                                      \
    const int brd = (wc * 32 + lr) * 64;                                       \
    const int g0  = (lkg ^ x) * 8;                                             \
    const int g1  = g0 ^ 32;

#define LDSA(s) (&lds[(s) * 24576])
#define LDSB(s) (&lds[(s) * 24576 + 16384])
#define STAGE_A(t, s, j) GLOAD16(Ast + (size_t)(t) * 64 + (size_t)(j) * 64 * DIM, \
                                 LDSA(s) + (j) * 4096 + wid * 512)
#define STAGE_B(t, s, j) GLOAD16(Bst + (size_t)(t) * 64 + (size_t)(j) * 64 * DIM, \
                                 LDSB(s) + (j) * 4096 + wid * 512)

__device__ __forceinline__ void gemm_1b(const _Float16* __restrict__ A,
                                        const _Float16* __restrict__ W,
                                        int row0, int col0,
                                        _Float16* lds, float4_t acc[8][2])
{
    GEMM_SETUP

    STAGE_A(0, 0, 0); STAGE_A(0, 0, 1); STAGE_A(0, 0, 2); STAGE_A(0, 0, 3);
    STAGE_B(0, 0, 0); STAGE_B(0, 0, 1);
    STAGE_A(1, 1, 0); STAGE_A(1, 1, 1); STAGE_A(1, 1, 2); STAGE_A(1, 1, 3);
    STAGE_B(1, 1, 0); STAGE_B(1, 1, 1);
    asm volatile("s_waitcnt vmcnt(6)" ::: "memory");
    __builtin_amdgcn_s_barrier();
    __builtin_amdgcn_sched_barrier(0);

    int s = 0, s2 = 2;
    for (int t = 0; t < 12; ++t) {
        const _Float16* Asl = LDSA(s);
        const _Float16* Bsl = LDSB(s);
        const bool pf = (t < 10);

        half8_t bf[2][2], af[8][2];
        bf[0][0] = *(const half8_t*)&Bsl[brd + g0];
        bf[0][1] = *(const half8_t*)&Bsl[brd + g1];
        bf[1][0] = *(const half8_t*)&Bsl[brd + 1024 + g0];
        bf[1][1] = *(const half8_t*)&Bsl[brd + 1024 + g1];
        #pragma unroll
        for (int i = 0; i < 8; ++i) {
            af[i][0] = *(const half8_t*)&Asl[ard + i * 1024 + g0];
            af[i][1] = *(const half8_t*)&Asl[ard + i * 1024 + g1];
        }
        if (pf) {
            STAGE_A(t + 2, s2, 0); STAGE_A(t + 2, s2, 1);
            STAGE_A(t + 2, s2, 2); STAGE_A(t + 2, s2, 3);
            STAGE_B(t + 2, s2, 0); STAGE_B(t + 2, s2, 1);
        }

        asm volatile("s_waitcnt lgkmcnt(0)" ::: "memory");
        __builtin_amdgcn_sched_barrier(0);
        __builtin_amdgcn_s_setprio(1);
        #pragma unroll
        for (int i = 0; i < 8; ++i)
            #pragma unroll
            for (int ni = 0; ni < 2; ++ni) {
                acc[i][ni] = MFMA16(af[i][0], bf[ni][0], acc[i][ni]);
                acc[i][ni] = MFMA16(af[i][1], bf[ni][1], acc[i][ni]);
            }
        __builtin_amdgcn_s_setprio(0);
        __builtin_amdgcn_sched_barrier(0);

        if (t < 11) {
            if (pf) asm volatile("s_waitcnt vmcnt(6)" ::: "memory");
            else    asm volatile("s_waitcnt vmcnt(0)" ::: "memory");
            __builtin_amdgcn_s_barrier();
            __builtin_amdgcn_sched_barrier(0);
        }
        s  = (s  == 2) ? 0 : s  + 1;
        s2 = (s2 == 2) ? 0 : s2 + 1;
    }
}

// ---------------------------------------------------------------------------
// Fused q/k/v projection: 1152 blocks (256x128 tiles) — gemm_1b
// ---------------------------------------------------------------------------
__global__ __launch_bounds__(512) void proj_qkv(
    const _Float16* __restrict__ xq16, const _Float16* __restrict__ xkv16,
    const _Float16* __restrict__ Wq16, const _Float16* __restrict__ Wk16,
    const _Float16* __restrict__ Wv16,
    _Float16* __restrict__ q16, _Float16* __restrict__ k16,
    _Float16* __restrict__ v16)
{
    __shared__ __align__(16) _Float16 lds[3 * 24576];   // 147456 B

    const int cpx = gridDim.x >> 3;                     // 1152/8 = 144
    int bid = (blockIdx.x & 7) * cpx + (blockIdx.x >> 3);

    const _Float16 *A, *W; _Float16* O; bool elu;
    int brow, bcol;
    if (bid < 768) {
        A = xq16; W = Wq16; O = q16; elu = true;
        brow = bid / 6; bcol = bid - brow * 6;
    } else {
        int u = bid - 768;
        int mat = u / 192;  u -= mat * 192;
        A = xkv16; W = mat ? Wv16 : Wk16; O = mat ? v16 : k16; elu = !mat;
        brow = u / 6; bcol = u - brow * 6;
    }
    const int row0 = brow * 256, col0 = bcol * 128;

    float4_t acc[8][2] = {};
    gemm_1b(A, W, row0, col0, lds, acc);

    const int wid = threadIdx.x >> 6, lane = threadIdx.x & 63;
    const int wr = wid >> 2, wc = wid & 3, lr = lane & 15, lkg = lane >> 4;
    #pragma unroll
    for (int mi = 0; mi < 8; ++mi) {
        #pragma unroll
        for (int ni = 0; ni < 2; ++ni) {
            #pragma unroll
            for (int e = 0; e < 4; ++e) {
                int r = row0 + wr * 128 + mi * 16 + lkg * 4 + e;
                int c = col0 + wc * 32 + ni * 16 + lr;
                float v = acc[mi][ni][e];
                if (elu) v = (v > 0.0f) ? (v + 1.0f) : __expf(v);  // elu(x)+1
                O[(size_t)r * DIM + c] = (_Float16)v;
            }
        }
    }
}

// ---------------------------------------------------------------------------
// out = attn16 @ Wo.T + bo  (fp32 output), 768 blocks — gemm_1b (propagated)
// ---------------------------------------------------------------------------
__global__ __launch_bounds__(512) void out_proj(
    const _Float16* __restrict__ a16, const _Float16* __restrict__ Wo16,
    const float* __restrict__ bo, float* __restrict__ out)
{
    __shared__ __align__(16) _Float16 lds[3 * 24576];

    const int cpx = gridDim.x >> 3;                     // 768/8 = 96
    int bid = (blockIdx.x & 7) * cpx + (blockIdx.x >> 3);
    const int brow = bid / 6, bcol = bid - brow * 6;
    const int row0 = brow * 256, col0 = bcol * 128;

    float4_t acc[8][2] = {};
    gemm_1b(a16, Wo16, row0, col0, lds, acc);

    const int wid = threadIdx.x >> 6, lane = threadIdx.x & 63;
    const int wr = wid >> 2, wc = wid & 3, lr = lane & 15, lkg = lane >> 4;
    #pragma unroll
    for (int mi = 0; mi < 8; ++mi) {
        #pragma unroll
        for (int ni = 0; ni < 2; ++ni) {
            #pragma unroll
            for (int e = 0; e < 4; ++e) {
                int r = row0 + wr * 128 + mi * 16 + lkg * 4 + e;
                int c = col0 + wc * 32 + ni * 16 + lr;
                out[(size_t)r * DIM + c] = acc[mi][ni][e] + bo[c];
            }
        }
    }
}

// ---------------------------------------------------------------------------
// kv_reduce: per (b,h): kvh[e][d] = sum_n v[n,e]*k[n,d];  ksum[d] = sum_n k[n,d]
// ---------------------------------------------------------------------------
__global__ __launch_bounds__(256) void kv_reduce(const _Float16* __restrict__ k16,
                                                 const _Float16* __restrict__ v16,
                                                 float* __restrict__ kvh,
                                                 float* __restrict__ ksum)
{
    __shared__ __align__(16) _Float16 K[128][64];
    __shared__ __align__(16) _Float16 V[128][64];
    const int chunk = blockIdx.x;   // 0..7
    const int bh    = blockIdx.y;   // 0..95
    const int b = bh / 12, h = bh % 12;
    const int tid = threadIdx.x;

    const size_t base = ((size_t)b * 1024 + (size_t)chunk * 128) * DIM + h * 64;
    #pragma unroll
    for (int j = 0; j < 4; ++j) {
        int idx = j * 256 + tid;
        int r = idx >> 3, c = (idx & 7) * 8;
        *(half8_t*)&K[r][c] = *(const half8_t*)&k16[base + (size_t)r * DIM + c];
        *(half8_t*)&V[r][c] = *(const half8_t*)&v16[base + (size_t)r * DIM + c];
    }
    __syncthreads();

    const int d0 = (tid & 15) * 4;
    const int e0 = (tid >> 4) * 4;
    float acc[4][4] = {};
    #pragma unroll 4
    for (int n = 0; n < 128; ++n) {
        half4_t kd = *(const half4_t*)&K[n][d0];
        half4_t ve = *(const half4_t*)&V[n][e0];
        #pragma unroll
        for (int i = 0; i < 4; ++i)
            #pragma unroll
            for (int j = 0; j < 4; ++j)
                acc[i][j] += (float)ve[i] * (float)kd[j];
    }
    float* kvp = kvh + (size_t)bh * 64 * 64;
    #pragma unroll
    for (int i = 0; i < 4; ++i)
        #pragma unroll
        for (int j = 0; j < 4; ++j)
            atomicAdd(&kvp[(e0 + i) * 64 + d0 + j], acc[i][j]);

    if (tid < 64) {
        float s = 0.0f;
        for (int n = 0; n < 128; ++n) s += (float)K[n][tid];
        atomicAdd(&ksum[bh * 64 + tid], s);
    }
}

// ---------------------------------------------------------------------------
// attn: z = 1/(q . ksum + 1e-6); attn = (q @ kv) * z   (in-place on q16)
// ---------------------------------------------------------------------------
__global__ __launch_bounds__(256) void attn_kernel(_Float16* __restrict__ q16,
                                                   const float* __restrict__ kvh,
                                                   const float* __restrict__ ksum)
{
    __shared__ __align__(16) _Float16 Q[128][72];
    __shared__ __align__(16) _Float16 Bv[64][72];
    __shared__ float S[64];
    __shared__ float Z[128];

    const int h    = blockIdx.x;        // 0..11
    const int rb   = blockIdx.y;        // 0..255
    const int row0 = rb * 128;
    const int b    = row0 >> 12;
    const int bh   = b * 12 + h;
    const int tid  = threadIdx.x;

    #pragma unroll
    for (int j = 0; j < 4; ++j) {
        int idx = j * 256 + tid;
        int r = idx >> 3, c = (idx & 7) * 8;
        *(half8_t*)&Q[r][c] =
            *(const half8_t*)&q16[(size_t)(row0 + r) * DIM + h * 64 + c];
    }
    #pragma unroll
    for (int j = 0; j < 4; ++j) {
        int idx = j * 256 + tid;
        int r = idx >> 4, c = (idx & 15) * 4;
        float4_t f = *(const float4_t*)&kvh[((size_t)bh * 64 + r) * 64 + c];
        half4_t hh;
        #pragma unroll
        for (int e = 0; e < 4; ++e) hh[e] = (_Float16)f[e];
        *(half4_t*)&Bv[r][c] = hh;
    }
    if (tid < 64) S[tid] = ksum[bh * 64 + tid];
    __syncthreads();

    if (tid < 128) {
        float dot = 0.0f;
        #pragma unroll 8
        for (int d = 0; d < 64; ++d) dot += (float)Q[tid][d] * S[d];
        Z[tid] = 1.0f / (dot + 1e-6f);
    }
    __syncthreads();

    const int w = tid >> 6, lane = tid & 63;
    const int lr = lane & 15, lkg = lane >> 4;
    float4_t acc[2][4] = {};
    #pragma unroll
    for (int kc = 0; kc < 2; ++kc) {
        half8_t aF[2], bF[4];
        #pragma unroll
        for (int mi = 0; mi < 2; ++mi)
            aF[mi] = *(const half8_t*)&Q[w * 32 + mi * 16 + lr][kc * 32 + lkg * 8];
        #pragma unroll
        for (int ni = 0; ni < 4; ++ni)
            bF[ni] = *(const half8_t*)&Bv[ni * 16 + lr][kc * 32 + lkg * 8];
        #pragma unroll
        for (int mi = 0; mi < 2; ++mi)
            #pragma unroll
            for (int ni = 0; ni < 4; ++ni)
                acc[mi][ni] = MFMA16(aF[mi], bF[ni], acc[mi][ni]);
    }
    #pragma unroll
    for (int mi = 0; mi < 2; ++mi) {
        #pragma unroll
        for (int ni = 0; ni < 4; ++ni) {
            #pragma unroll
            for (int e = 0; e < 4; ++e) {
                int r = w * 32 + mi * 16 + lkg * 4 + e;
                float v = acc[mi][ni][e] * Z[r];
                q16[(size_t)(row0 + r) * DIM + h * 64 + ni * 16 + lr] = (_Float16)v;
            }
        }
    }
}

// ---------------------------------------------------------------------------
extern "C" void kernel_launch(void* const* d_in, const int* in_sizes, int n_in,
                              void* d_out, int out_size, void* d_ws, size_t ws_size,
                              hipStream_t stream)
{
    const float* xq  = (const float*)d_in[0];  // [8,4096,768]
    const float* xkv = (const float*)d_in[1];  // [8,1024,768]
    const float* Wq  = (const float*)d_in[2];
    const float* Wk  = (const float*)d_in[3];
    const float* Wv  = (const float*)d_in[4];
    const float* Wo  = (const float*)d_in[5];
    const float* bo  = (const float*)d_in[6];

    // ---- workspace layout (~69 MB) ----
    char* ws = (char*)d_ws;
    const size_t SZ_Q16   = (size_t)32768 * 768 * 2;   // 50,331,648
    const size_t SZ_XKV16 = (size_t)8192 * 768 * 2;    // 12,582,912
    const size_t SZ_W16   = (size_t)768 * 768 * 2;     //  1,179,648
    const size_t SZ_KVH   = (size_t)96 * 64 * 64 * 4;  //  1,572,864
    const size_t SZ_KSUM  = (size_t)96 * 64 * 4;       //     24,576

    _Float16* q16   = (_Float16*)(ws);
    _Float16* xkv16 = (_Float16*)(ws + SZ_Q16);
    _Float16* Wq16  = (_Float16*)(ws + SZ_Q16 + SZ_XKV16);            // 4 contiguous
    _Float16* Wk16  = (_Float16*)(ws + SZ_Q16 + SZ_XKV16 + SZ_W16);
    _Float16* Wv16  = (_Float16*)(ws + SZ_Q16 + SZ_XKV16 + 2 * SZ_W16);
    _Float16* Wo16  = (_Float16*)(ws + SZ_Q16 + SZ_XKV16 + 3 * SZ_W16);
    float*    kvh   = (float*)   (ws + SZ_Q16 + SZ_XKV16 + 4 * SZ_W16);
    float*    ksum  = (float*)   (ws + SZ_Q16 + SZ_XKV16 + 4 * SZ_W16 + SZ_KVH);

    // ---- d_out aliasing: xq16 consumed by proj_qkv; k16/v16 by kv_reduce;
    //      all dead before out_proj overwrites d_out. ----
    char* ob = (char*)d_out;
    _Float16* xq16 = (_Float16*)(ob);                       // 50,331,648
    _Float16* k16  = (_Float16*)(ob + 50331648);            // 12,582,912
    _Float16* v16  = (_Float16*)(ob + 50331648 + 12582912); // 12,582,912
    float*    out  = (float*)d_out;

    // 1) one fused cast + zero launch
    cast_all<<<16902, 256, 0, stream>>>(xq, xkv, Wq, Wk, Wv, Wo,
                                        xq16, xkv16, Wq16, kvh);

    // 2) fused projections: q = elu1(xq@Wq.T), k = elu1(xkv@Wk.T), v = xkv@Wv.T
    proj_qkv<<<1152, 512, 0, stream>>>(xq16, xkv16, Wq16, Wk16, Wv16,
                                       q16, k16, v16);

    // 3) linear attention
    kv_reduce<<<dim3(8, 96), 256, 0, stream>>>(k16, v16, kvh, ksum);
    attn_kernel<<<dim3(12, 256), 256, 0, stream>>>(q16, kvh, ksum);

    // 4) out = attn @ Wo.T + bo  (fp32 output)
    out_proj<<<768, 512, 0, stream>>>(q16, Wo16, bo, out);
}

// Round 16
// 212.437 us; speedup vs baseline: 1.2026x; 1.0186x over previous
//
#include <hip/hip_runtime.h>

typedef _Float16 half8_t __attribute__((ext_vector_type(8)));
typedef _Float16 half4_t __attribute__((ext_vector_type(4)));
typedef float    float4_t __attribute__((ext_vector_type(4)));

#define DIM 768

// async global->LDS, 16B per lane; LDS dest is wave-uniform base + lane*16
#define GLOAD16(g, l) __builtin_amdgcn_global_load_lds(                        \
    (const __attribute__((address_space(1))) void*)(g),                        \
    (__attribute__((address_space(3))) void*)(l), 16, 0, 0)

#define MFMA16(a, b, c) __builtin_amdgcn_mfma_f32_16x16x32_f16((a), (b), (c), 0, 0, 0)

// ---------------------------------------------------------------------------
// one fused cast launch: xq | xkv | weights | zero kvh+ksum (memset folded)
// ---------------------------------------------------------------------------
__global__ __launch_bounds__(256) void cast_all(
    const float* __restrict__ xq,  const float* __restrict__ xkv,
    const float* __restrict__ Wq,  const float* __restrict__ Wk,
    const float* __restrict__ Wv,  const float* __restrict__ Wo,
    _Float16* __restrict__ dq, _Float16* __restrict__ dkv,
    _Float16* __restrict__ dW /* 4 matrices contiguous */,
    float* __restrict__ kvz /* kvh+ksum region, 399,360 floats */)
{
    int i = blockIdx.x * 256 + threadIdx.x;
    if (i >= 4227072) {                        // zero kvh/ksum tail
        int z = i - 4227072;
        if (z < 99840) {
            float4_t zf = {0.f, 0.f, 0.f, 0.f};
            *(float4_t*)&kvz[(size_t)z * 4] = zf;
        }
        return;
    }
    const float* s; _Float16* d; int off;
    if (i < 3145728)      { s = xq;  d = dq;  off = i; }
    else if (i < 3932160) { s = xkv; d = dkv; off = i - 3145728; }
    else {
        int j = i - 3932160;                   // 0..294911
        int w = j / 73728;  off = j - w * 73728;
        s = (w == 0) ? Wq : (w == 1) ? Wk : (w == 2) ? Wv : Wo;
        d = dW + (size_t)w * 589824;
    }
    float4_t f0 = *(const float4_t*)&s[(size_t)off * 8];
    float4_t f1 = *(const float4_t*)&s[(size_t)off * 8 + 4];
    half8_t h;
    #pragma unroll
    for (int e = 0; e < 4; ++e) { h[e] = (_Float16)f0[e]; h[e + 4] = (_Float16)f1[e]; }
    *(half8_t*)&d[(size_t)off * 8] = h;
}

// ---------------------------------------------------------------------------
// gemm_1b — r14/r15 measured-best cadence + r16 wave-shape change:
// 256x128 tile, BK=64, 512 thr = 8 waves, now 4M x 2N (per-wave C 64x64).
// Per-wave ds_read drops 20 -> 16 b128 (A read-amplification 4x -> 2x;
// per-wave bytes (m+n) minimized by the square wave tile) — the LDS read
// pipe (~160KB/tile at 2Mx4N, ~128KB at 4Mx2N) was the largest per-tile
// cost term. Everything else (staging, 3 slots, XOR swizzle, stage t+2,
// counted vmcnt(6), ONE barrier/tile, setprio) is byte-identical to r15.
// ---------------------------------------------------------------------------
#define GEMM_SETUP                                                             \
    const int tid  = threadIdx.x;                                              \
    const int wid  = tid >> 6, lane = tid & 63;                                \
    const int wr   = wid >> 1;            /* 0..3 : 64-row band   */           \
    const int wc   = wid & 1;             /* 0..1 : 64-col band   */           \
    const int lr   = lane & 15;                                                \
    const int lkg  = lane >> 4;                                                \
    const int x    = lr & 7;                                                   \
    const int  srow = wid * 8 + (lane >> 3);                                   \
    const int  sg   = ((lane & 7) ^ (lane >> 3)) * 8;                          \
    const _Float16* Ast = A + (size_t)(row0 + srow) * DIM + sg;                \
    const _Float16* Bst = W + (size_t)(col0 + srow) * DIM + sg;                \
    const int ard = (wr * 64 + lr) * 64;  /* A row wr*64 + mi*16 + lr */       \
    const int brd = (wc * 64 + lr) * 64;  /* B row wc*64 + ni*16 + lr */       \
    const int g0  = (lkg ^ x) * 8;                                             \
    const int g1  = g0 ^ 32;

#define LDSA(s) (&lds[(s) * 24576])
#define LDSB(s) (&lds[(s) * 24576 + 16384])
#define STAGE_A(t, s, j) GLOAD16(Ast + (size_t)(t) * 64 + (size_t)(j) * 64 * DIM, \
                                 LDSA(s) + (j) * 4096 + wid * 512)
#define STAGE_B(t, s, j) GLOAD16(Bst + (size_t)(t) * 64 + (size_t)(j) * 64 * DIM, \
                                 LDSB(s) + (j) * 4096 + wid * 512)

__device__ __forceinline__ void gemm_1b(const _Float16* __restrict__ A,
                                        const _Float16* __restrict__ W,
                                        int row0, int col0,
                                        _Float16* lds, float4_t acc[4][4])
{
    GEMM_SETUP

    STAGE_A(0, 0, 0); STAGE_A(0, 0, 1); STAGE_A(0, 0, 2); STAGE_A(0, 0, 3);
    STAGE_B(0, 0, 0); STAGE_B(0, 0, 1);
    STAGE_A(1, 1, 0); STAGE_A(1, 1, 1); STAGE_A(1, 1, 2); STAGE_A(1, 1, 3);
    STAGE_B(1, 1, 0); STAGE_B(1, 1, 1);
    asm volatile("s_waitcnt vmcnt(6)" ::: "memory");
    __builtin_amdgcn_s_barrier();
    __builtin_amdgcn_sched_barrier(0);

    int s = 0, s2 = 2;
    for (int t = 0; t < 12; ++t) {
        const _Float16* Asl = LDSA(s);
        const _Float16* Bsl = LDSB(s);
        const bool pf = (t < 10);

        // frags: A rows wr*64 + mi*16 + lr, B rows (out-cols) wc*64 + ni*16 + lr
        half8_t af[4][2], bf[4][2];
        #pragma unroll
        for (int i = 0; i < 4; ++i) {
            af[i][0] = *(const half8_t*)&Asl[ard + i * 1024 + g0];
            af[i][1] = *(const half8_t*)&Asl[ard + i * 1024 + g1];
        }
        #pragma unroll
        for (int i = 0; i < 4; ++i) {
            bf[i][0] = *(const half8_t*)&Bsl[brd + i * 1024 + g0];
            bf[i][1] = *(const half8_t*)&Bsl[brd + i * 1024 + g1];
        }
        if (pf) {
            STAGE_A(t + 2, s2, 0); STAGE_A(t + 2, s2, 1);
            STAGE_A(t + 2, s2, 2); STAGE_A(t + 2, s2, 3);
            STAGE_B(t + 2, s2, 0); STAGE_B(t + 2, s2, 1);
        }

        asm volatile("s_waitcnt lgkmcnt(0)" ::: "memory");
        __builtin_amdgcn_sched_barrier(0);
        __builtin_amdgcn_s_setprio(1);
        #pragma unroll
        for (int mi = 0; mi < 4; ++mi)
            #pragma unroll
            for (int ni = 0; ni < 4; ++ni) {
                acc[mi][ni] = MFMA16(af[mi][0], bf[ni][0], acc[mi][ni]);
                acc[mi][ni] = MFMA16(af[mi][1], bf[ni][1], acc[mi][ni]);
            }
        __builtin_amdgcn_s_setprio(0);
        __builtin_amdgcn_sched_barrier(0);

        if (t < 11) {
            if (pf) asm volatile("s_waitcnt vmcnt(6)" ::: "memory");
            else    asm volatile("s_waitcnt vmcnt(0)" ::: "memory");
            __builtin_amdgcn_s_barrier();
            __builtin_amdgcn_sched_barrier(0);
        }
        s  = (s  == 2) ? 0 : s  + 1;
        s2 = (s2 == 2) ? 0 : s2 + 1;
    }
}

// ---------------------------------------------------------------------------
// Fused q/k/v projection: 1152 blocks (256x128 tiles) — gemm_1b 4Mx2N
// ---------------------------------------------------------------------------
__global__ __launch_bounds__(512) void proj_qkv(
    const _Float16* __restrict__ xq16, const _Float16* __restrict__ xkv16,
    const _Float16* __restrict__ Wq16, const _Float16* __restrict__ Wk16,
    const _Float16* __restrict__ Wv16,
    _Float16* __restrict__ q16, _Float16* __restrict__ k16,
    _Float16* __restrict__ v16)
{
    __shared__ __align__(16) _Float16 lds[3 * 24576];   // 147456 B

    const int cpx = gridDim.x >> 3;                     // 1152/8 = 144
    int bid = (blockIdx.x & 7) * cpx + (blockIdx.x >> 3);

    const _Float16 *A, *W; _Float16* O; bool elu;
    int brow, bcol;
    if (bid < 768) {
        A = xq16; W = Wq16; O = q16; elu = true;
        brow = bid / 6; bcol = bid - brow * 6;
    } else {
        int u = bid - 768;
        int mat = u / 192;  u -= mat * 192;
        A = xkv16; W = mat ? Wv16 : Wk16; O = mat ? v16 : k16; elu = !mat;
        brow = u / 6; bcol = u - brow * 6;
    }
    const int row0 = brow * 256, col0 = bcol * 128;

    float4_t acc[4][4] = {};
    gemm_1b(A, W, row0, col0, lds, acc);

    const int wid = threadIdx.x >> 6, lane = threadIdx.x & 63;
    const int wr = wid >> 1, wc = wid & 1, lr = lane & 15, lkg = lane >> 4;
    #pragma unroll
    for (int mi = 0; mi < 4; ++mi) {
        #pragma unroll
        for (int ni = 0; ni < 4; ++ni) {
            #pragma unroll
            for (int e = 0; e < 4; ++e) {
                int r = row0 + wr * 64 + mi * 16 + lkg * 4 + e;
                int c = col0 + wc * 64 + ni * 16 + lr;
                float v = acc[mi][ni][e];
                if (elu) v = (v > 0.0f) ? (v + 1.0f) : __expf(v);  // elu(x)+1
                O[(size_t)r * DIM + c] = (_Float16)v;
            }
        }
    }
}

// ---------------------------------------------------------------------------
// out = attn16 @ Wo.T + bo  (fp32 output), 768 blocks — gemm_1b 4Mx2N
// ---------------------------------------------------------------------------
__global__ __launch_bounds__(512) void out_proj(
    const _Float16* __restrict__ a16, const _Float16* __restrict__ Wo16,
    const float* __restrict__ bo, float* __restrict__ out)
{
    __shared__ __align__(16) _Float16 lds[3 * 24576];

    const int cpx = gridDim.x >> 3;                     // 768/8 = 96
    int bid = (blockIdx.x & 7) * cpx + (blockIdx.x >> 3);
    const int brow = bid / 6, bcol = bid - brow * 6;
    const int row0 = brow * 256, col0 = bcol * 128;

    float4_t acc[4][4] = {};
    gemm_1b(a16, Wo16, row0, col0, lds, acc);

    const int wid = threadIdx.x >> 6, lane = threadIdx.x & 63;
    const int wr = wid >> 1, wc = wid & 1, lr = lane & 15, lkg = lane >> 4;
    #pragma unroll
    for (int mi = 0; mi < 4; ++mi) {
        #pragma unroll
        for (int ni = 0; ni < 4; ++ni) {
            #pragma unroll
            for (int e = 0; e < 4; ++e) {
                int r = row0 + wr * 64 + mi * 16 + lkg * 4 + e;
                int c = col0 + wc * 64 + ni * 16 + lr;
                out[(size_t)r * DIM + c] = acc[mi][ni][e] + bo[c];
            }
        }
    }
}

// ---------------------------------------------------------------------------
// kv_reduce: per (b,h): kvh[e][d] = sum_n v[n,e]*k[n,d];  ksum[d] = sum_n k[n,d]
// ---------------------------------------------------------------------------
__global__ __launch_bounds__(256) void kv_reduce(const _Float16* __restrict__ k16,
                                                 const _Float16* __restrict__ v16,
                                                 float* __restrict__ kvh,
                                                 float* __restrict__ ksum)
{
    __shared__ __align__(16) _Float16 K[128][64];
    __shared__ __align__(16) _Float16 V[128][64];
    const int chunk = blockIdx.x;   // 0..7
    const int bh    = blockIdx.y;   // 0..95
    const int b = bh / 12, h = bh % 12;
    const int tid = threadIdx.x;

    const size_t base = ((size_t)b * 1024 + (size_t)chunk * 128) * DIM + h * 64;
    #pragma unroll
    for (int j = 0; j < 4; ++j) {
        int idx = j * 256 + tid;
        int r = idx >> 3, c = (idx & 7) * 8;
        *(half8_t*)&K[r][c] = *(const half8_t*)&k16[base + (size_t)r * DIM + c];
        *(half8_t*)&V[r][c] = *(const half8_t*)&v16[base + (size_t)r * DIM + c];
    }
    __syncthreads();

    const int d0 = (tid & 15) * 4;
    const int e0 = (tid >> 4) * 4;
    float acc[4][4] = {};
    #pragma unroll 4
    for (int n = 0; n < 128; ++n) {
        half4_t kd = *(const half4_t*)&K[n][d0];
        half4_t ve = *(const half4_t*)&V[n][e0];
        #pragma unroll
        for (int i = 0; i < 4; ++i)
            #pragma unroll
            for (int j = 0; j < 4; ++j)
                acc[i][j] += (float)ve[i] * (float)kd[j];
    }
    float* kvp = kvh + (size_t)bh * 64 * 64;
    #pragma unroll
    for (int i = 0; i < 4; ++i)
        #pragma unroll
        for (int j = 0; j < 4; ++j)
            atomicAdd(&kvp[(e0 + i) * 64 + d0 + j], acc[i][j]);

    if (tid < 64) {
        float s = 0.0f;
        for (int n = 0; n < 128; ++n) s += (float)K[n][tid];
        atomicAdd(&ksum[bh * 64 + tid], s);
    }
}

// ---------------------------------------------------------------------------
// attn: z = 1/(q . ksum + 1e-6); attn = (q @ kv) * z   (in-place on q16)
// ---------------------------------------------------------------------------
__global__ __launch_bounds__(256) void attn_kernel(_Float16* __restrict__ q16,
                                                   const float* __restrict__ kvh,
                                                   const float* __restrict__ ksum)
{
    __shared__ __align__(16) _Float16 Q[128][72];
    __shared__ __align__(16) _Float16 Bv[64][72];
    __shared__ float S[64];
    __shared__ float Z[128];

    const int h    = blockIdx.x;        // 0..11
    const int rb   = blockIdx.y;        // 0..255
    const int row0 = rb * 128;
    const int b    = row0 >> 12;
    const int bh   = b * 12 + h;
    const int tid  = threadIdx.x;

    #pragma unroll
    for (int j = 0; j < 4; ++j) {
        int idx = j * 256 + tid;
        int r = idx >> 3, c = (idx & 7) * 8;
        *(half8_t*)&Q[r][c] =
            *(const half8_t*)&q16[(size_t)(row0 + r) * DIM + h * 64 + c];
    }
    #pragma unroll
    for (int j = 0; j < 4; ++j) {
        int idx = j * 256 + tid;
        int r = idx >> 4, c = (idx & 15) * 4;
        float4_t f = *(const float4_t*)&kvh[((size_t)bh * 64 + r) * 64 + c];
        half4_t hh;
        #pragma unroll
        for (int e = 0; e < 4; ++e) hh[e] = (_Float16)f[e];
        *(half4_t*)&Bv[r][c] = hh;
    }
    if (tid < 64) S[tid] = ksum[bh * 64 + tid];
    __syncthreads();

    if (tid < 128) {
        float dot = 0.0f;
        #pragma unroll 8
        for (int d = 0; d < 64; ++d) dot += (float)Q[tid][d] * S[d];
        Z[tid] = 1.0f / (dot + 1e-6f);
    }
    __syncthreads();

    const int w = tid >> 6, lane = tid & 63;
    const int lr = lane & 15, lkg = lane >> 4;
    float4_t acc[2][4] = {};
    #pragma unroll
    for (int kc = 0; kc < 2; ++kc) {
        half8_t aF[2], bF[4];
        #pragma unroll
        for (int mi = 0; mi < 2; ++mi)
            aF[mi] = *(const half8_t*)&Q[w * 32 + mi * 16 + lr][kc * 32 + lkg * 8];
        #pragma unroll
        for (int ni = 0; ni < 4; ++ni)
            bF[ni] = *(const half8_t*)&Bv[ni * 16 + lr][kc * 32 + lkg * 8];
        #pragma unroll
        for (int mi = 0; mi < 2; ++mi)
            #pragma unroll
            for (int ni = 0; ni < 4; ++ni)
                acc[mi][ni] = MFMA16(aF[mi], bF[ni], acc[mi][ni]);
    }
    #pragma unroll
    for (int mi = 0; mi < 2; ++mi) {
        #pragma unroll
        for (int ni = 0; ni < 4; ++ni) {
            #pragma unroll
            for (int e = 0; e < 4; ++e) {
                int r = w * 32 + mi * 16 + lkg * 4 + e;
                float v = acc[mi][ni][e] * Z[r];
                q16[(size_t)(row0 + r) * DIM + h * 64 + ni * 16 + lr] = (_Float16)v;
            }
        }
    }
}

// ---------------------------------------------------------------------------
extern "C" void kernel_launch(void* const* d_in, const int* in_sizes, int n_in,
                              void* d_out, int out_size, void* d_ws, size_t ws_size,
                              hipStream_t stream)
{
    const float* xq  = (const float*)d_in[0];  // [8,4096,768]
    const float* xkv = (const float*)d_in[1];  // [8,1024,768]
    const float* Wq  = (const float*)d_in[2];
    const float* Wk  = (const float*)d_in[3];
    const float* Wv  = (const float*)d_in[4];
    const float* Wo  = (const float*)d_in[5];
    const float* bo  = (const float*)d_in[6];

    // ---- workspace layout (~69 MB) ----
    char* ws = (char*)d_ws;
    const size_t SZ_Q16   = (size_t)32768 * 768 * 2;   // 50,331,648
    const size_t SZ_XKV16 = (size_t)8192 * 768 * 2;    // 12,582,912
    const size_t SZ_W16   = (size_t)768 * 768 * 2;     //  1,179,648
    const size_t SZ_KVH   = (size_t)96 * 64 * 64 * 4;  //  1,572,864
    const size_t SZ_KSUM  = (size_t)96 * 64 * 4;       //     24,576

    _Float16* q16   = (_Float16*)(ws);
    _Float16* xkv16 = (_Float16*)(ws + SZ_Q16);
    _Float16* Wq16  = (_Float16*)(ws + SZ_Q16 + SZ_XKV16);            // 4 contiguous
    _Float16* Wk16  = (_Float16*)(ws + SZ_Q16 + SZ_XKV16 + SZ_W16);
    _Float16* Wv16  = (_Float16*)(ws + SZ_Q16 + SZ_XKV16 + 2 * SZ_W16);
    _Float16* Wo16  = (_Float16*)(ws + SZ_Q16 + SZ_XKV16 + 3 * SZ_W16);
    float*    kvh   = (float*)   (ws + SZ_Q16 + SZ_XKV16 + 4 * SZ_W16);
    float*    ksum  = (float*)   (ws + SZ_Q16 + SZ_XKV16 + 4 * SZ_W16 + SZ_KVH);

    // ---- d_out aliasing: xq16 consumed by proj_qkv; k16/v16 by kv_reduce;
    //      all dead before out_proj overwrites d_out. ----
    char* ob = (char*)d_out;
    _Float16* xq16 = (_Float16*)(ob);                       // 50,331,648
    _Float16* k16  = (_Float16*)(ob + 50331648);            // 12,582,912
    _Float16* v16  = (_Float16*)(ob + 50331648 + 12582912); // 12,582,912
    float*    out  = (float*)d_out;

    // 1) one fused cast + zero launch
    cast_all<<<16902, 256, 0, stream>>>(xq, xkv, Wq, Wk, Wv, Wo,
                                        xq16, xkv16, Wq16, kvh);

    // 2) fused projections: q = elu1(xq@Wq.T), k = elu1(xkv@Wk.T), v = xkv@Wv.T
    proj_qkv<<<1152, 512, 0, stream>>>(xq16, xkv16, Wq16, Wk16, Wv16,
                                       q16, k16, v16);

    // 3) linear attention
    kv_reduce<<<dim3(8, 96), 256, 0, stream>>>(k16, v16, kvh, ksum);
    attn_kernel<<<dim3(12, 256), 256, 0, stream>>>(q16, kvh, ksum);

    // 4) out = attn @ Wo.T + bo  (fp32 output)
    out_proj<<<768, 512, 0, stream>>>(q16, Wo16, bo, out);
}

// Round 17
// 212.425 us; speedup vs baseline: 1.2027x; 1.0001x over previous
//
#include <hip/hip_runtime.h>

typedef _Float16 half8_t __attribute__((ext_vector_type(8)));
typedef _Float16 half4_t __attribute__((ext_vector_type(4)));
typedef float    float4_t __attribute__((ext_vector_type(4)));

#define DIM 768

// async global->LDS, 16B per lane; LDS dest is wave-uniform base + lane*16
#define GLOAD16(g, l) __builtin_amdgcn_global_load_lds(                        \
    (const __attribute__((address_space(1))) void*)(g),                        \
    (__attribute__((address_space(3))) void*)(l), 16, 0, 0)

#define MFMA16(a, b, c) __builtin_amdgcn_mfma_f32_16x16x32_f16((a), (b), (c), 0, 0, 0)

// ---------------------------------------------------------------------------
// one fused cast launch: xq | xkv | weights | zero kvh+ksum (memset folded)
// ---------------------------------------------------------------------------
__global__ __launch_bounds__(256) void cast_all(
    const float* __restrict__ xq,  const float* __restrict__ xkv,
    const float* __restrict__ Wq,  const float* __restrict__ Wk,
    const float* __restrict__ Wv,  const float* __restrict__ Wo,
    _Float16* __restrict__ dq, _Float16* __restrict__ dkv,
    _Float16* __restrict__ dW /* 4 matrices contiguous */,
    float* __restrict__ kvz /* kvh+ksum region, 399,360 floats */)
{
    int i = blockIdx.x * 256 + threadIdx.x;
    if (i >= 4227072) {                        // zero kvh/ksum tail
        int z = i - 4227072;
        if (z < 99840) {
            float4_t zf = {0.f, 0.f, 0.f, 0.f};
            *(float4_t*)&kvz[(size_t)z * 4] = zf;
        }
        return;
    }
    const float* s; _Float16* d; int off;
    if (i < 3145728)      { s = xq;  d = dq;  off = i; }
    else if (i < 3932160) { s = xkv; d = dkv; off = i - 3145728; }
    else {
        int j = i - 3932160;                   // 0..294911
        int w = j / 73728;  off = j - w * 73728;
        s = (w == 0) ? Wq : (w == 1) ? Wk : (w == 2) ? Wv : Wo;
        d = dW + (size_t)w * 589824;
    }
    float4_t f0 = *(const float4_t*)&s[(size_t)off * 8];
    float4_t f1 = *(const float4_t*)&s[(size_t)off * 8 + 4];
    half8_t h;
    #pragma unroll
    for (int e = 0; e < 4; ++e) { h[e] = (_Float16)f0[e]; h[e + 4] = (_Float16)f1[e]; }
    *(half8_t*)&d[(size_t)off * 8] = h;
}

// ---------------------------------------------------------------------------
// gemm_1b — r16 core (4Mx2N waves, one barrier/tile) + r17 change: NO
// explicit lgkmcnt(0)/sched_barrier before the MFMA cluster. The ds_reads
// are plain loads (not inline asm), so the compiler emits fine-grained
// per-consumer lgkmcnt and can interleave ds_read latency under the MFMA
// stream (rule #18 applies only to asm ds_reads). Correctness unchanged:
// boundary vmcnt asm ("memory") still fences reads from hoisting above the
// slot-landing point; ONE barrier/tile; counted vmcnt(6) never 0 until tail.
// ---------------------------------------------------------------------------
#define GEMM_SETUP                                                             \
    const int tid  = threadIdx.x;                                              \
    const int wid  = tid >> 6, lane = tid & 63;                                \
    const int wr   = wid >> 1;            /* 0..3 : 64-row band   */           \
    const int wc   = wid & 1;             /* 0..1 : 64-col band   */           \
    const int lr   = lane & 15;                                                \
    const int lkg  = lane >> 4;                                                \
    const int x    = lr & 7;                                                   \
    const int  srow = wid * 8 + (lane >> 3);                                   \
    const int  sg   = ((lane & 7) ^ (lane >> 3)) * 8;                          \
    const _Float16* Ast = A + (size_t)(row0 + srow) * DIM + sg;                \
    const _Float16* Bst = W + (size_t)(col0 + srow) * DIM + sg;                \
    const int ard = (wr * 64 + lr) * 64;  /* A row wr*64 + mi*16 + lr */       \
    const int brd = (wc * 64 + lr) * 64;  /* B row wc*64 + ni*16 + lr */       \
    const int g0  = (lkg ^ x) * 8;                                             \
    const int g1  = g0 ^ 32;

#define LDSA(s) (&lds[(s) * 24576])
#define LDSB(s) (&lds[(s) * 24576 + 16384])
#define STAGE_A(t, s, j) GLOAD16(Ast + (size_t)(t) * 64 + (size_t)(j) * 64 * DIM, \
                                 LDSA(s) + (j) * 4096 + wid * 512)
#define STAGE_B(t, s, j) GLOAD16(Bst + (size_t)(t) * 64 + (size_t)(j) * 64 * DIM, \
                                 LDSB(s) + (j) * 4096 + wid * 512)

__device__ __forceinline__ void gemm_1b(const _Float16* __restrict__ A,
                                        const _Float16* __restrict__ W,
                                        int row0, int col0,
                                        _Float16* lds, float4_t acc[4][4])
{
    GEMM_SETUP

    STAGE_A(0, 0, 0); STAGE_A(0, 0, 1); STAGE_A(0, 0, 2); STAGE_A(0, 0, 3);
    STAGE_B(0, 0, 0); STAGE_B(0, 0, 1);
    STAGE_A(1, 1, 0); STAGE_A(1, 1, 1); STAGE_A(1, 1, 2); STAGE_A(1, 1, 3);
    STAGE_B(1, 1, 0); STAGE_B(1, 1, 1);
    asm volatile("s_waitcnt vmcnt(6)" ::: "memory");
    __builtin_amdgcn_s_barrier();
    __builtin_amdgcn_sched_barrier(0);

    int s = 0, s2 = 2;
    for (int t = 0; t < 12; ++t) {
        const _Float16* Asl = LDSA(s);
        const _Float16* Bsl = LDSB(s);
        const bool pf = (t < 10);

        // frags: A rows wr*64 + mi*16 + lr, B rows (out-cols) wc*64 + ni*16 + lr
        half8_t af[4][2], bf[4][2];
        #pragma unroll
        for (int i = 0; i < 4; ++i) {
            af[i][0] = *(const half8_t*)&Asl[ard + i * 1024 + g0];
            af[i][1] = *(const half8_t*)&Asl[ard + i * 1024 + g1];
        }
        #pragma unroll
        for (int i = 0; i < 4; ++i) {
            bf[i][0] = *(const half8_t*)&Bsl[brd + i * 1024 + g0];
            bf[i][1] = *(const half8_t*)&Bsl[brd + i * 1024 + g1];
        }
        if (pf) {
            STAGE_A(t + 2, s2, 0); STAGE_A(t + 2, s2, 1);
            STAGE_A(t + 2, s2, 2); STAGE_A(t + 2, s2, 3);
            STAGE_B(t + 2, s2, 0); STAGE_B(t + 2, s2, 1);
        }

        // r17: no explicit lgkmcnt(0)/sched_barrier here — compiler emits
        // fine-grained lgkmcnt per MFMA operand and overlaps reads w/ MFMAs.
        __builtin_amdgcn_s_setprio(1);
        #pragma unroll
        for (int mi = 0; mi < 4; ++mi)
            #pragma unroll
            for (int ni = 0; ni < 4; ++ni) {
                acc[mi][ni] = MFMA16(af[mi][0], bf[ni][0], acc[mi][ni]);
                acc[mi][ni] = MFMA16(af[mi][1], bf[ni][1], acc[mi][ni]);
            }
        __builtin_amdgcn_s_setprio(0);

        if (t < 11) {
            if (pf) asm volatile("s_waitcnt vmcnt(6)" ::: "memory");
            else    asm volatile("s_waitcnt vmcnt(0)" ::: "memory");
            __builtin_amdgcn_s_barrier();
            __builtin_amdgcn_sched_barrier(0);
        }
        s  = (s  == 2) ? 0 : s  + 1;
        s2 = (s2 == 2) ? 0 : s2 + 1;
    }
}

// ---------------------------------------------------------------------------
// Fused q/k/v projection: 1152 blocks (256x128 tiles) — gemm_1b 4Mx2N
// ---------------------------------------------------------------------------
__global__ __launch_bounds__(512) void proj_qkv(
    const _Float16* __restrict__ xq16, const _Float16* __restrict__ xkv16,
    const _Float16* __restrict__ Wq16, const _Float16* __restrict__ Wk16,
    const _Float16* __restrict__ Wv16,
    _Float16* __restrict__ q16, _Float16* __restrict__ k16,
    _Float16* __restrict__ v16)
{
    __shared__ __align__(16) _Float16 lds[3 * 24576];   // 147456 B

    const int cpx = gridDim.x >> 3;                     // 1152/8 = 144
    int bid = (blockIdx.x & 7) * cpx + (blockIdx.x >> 3);

    const _Float16 *A, *W; _Float16* O; bool elu;
    int brow, bcol;
    if (bid < 768) {
        A = xq16; W = Wq16; O = q16; elu = true;
        brow = bid / 6; bcol = bid - brow * 6;
    } else {
        int u = bid - 768;
        int mat = u / 192;  u -= mat * 192;
        A = xkv16; W = mat ? Wv16 : Wk16; O = mat ? v16 : k16; elu = !mat;
        brow = u / 6; bcol = u - brow * 6;
    }
    const int row0 = brow * 256, col0 = bcol * 128;

    float4_t acc[4][4] = {};
    gemm_1b(A, W, row0, col0, lds, acc);

    const int wid = threadIdx.x >> 6, lane = threadIdx.x & 63;
    const int wr = wid >> 1, wc = wid & 1, lr = lane & 15, lkg = lane >> 4;
    #pragma unroll
    for (int mi = 0; mi < 4; ++mi) {
        #pragma unroll
        for (int ni = 0; ni < 4; ++ni) {
            #pragma unroll
            for (int e = 0; e < 4; ++e) {
                int r = row0 + wr * 64 + mi * 16 + lkg * 4 + e;
                int c = col0 + wc * 64 + ni * 16 + lr;
                float v = acc[mi][ni][e];
                if (elu) v = (v > 0.0f) ? (v + 1.0f) : __expf(v);  // elu(x)+1
                O[(size_t)r * DIM + c] = (_Float16)v;
            }
        }
    }
}

// ---------------------------------------------------------------------------
// out = attn16 @ Wo.T + bo  (fp32 output), 768 blocks — gemm_1b 4Mx2N
// ---------------------------------------------------------------------------
__global__ __launch_bounds__(512) void out_proj(
    const _Float16* __restrict__ a16, const _Float16* __restrict__ Wo16,
    const float* __restrict__ bo, float* __restrict__ out)
{
    __shared__ __align__(16) _Float16 lds[3 * 24576];

    const int cpx = gridDim.x >> 3;                     // 768/8 = 96
    int bid = (blockIdx.x & 7) * cpx + (blockIdx.x >> 3);
    const int brow = bid / 6, bcol = bid - brow * 6;
    const int row0 = brow * 256, col0 = bcol * 128;

    float4_t acc[4][4] = {};
    gemm_1b(a16, Wo16, row0, col0, lds, acc);

    const int wid = threadIdx.x >> 6, lane = threadIdx.x & 63;
    const int wr = wid >> 1, wc = wid & 1, lr = lane & 15, lkg = lane >> 4;
    #pragma unroll
    for (int mi = 0; mi < 4; ++mi) {
        #pragma unroll
        for (int ni = 0; ni < 4; ++ni) {
            #pragma unroll
            for (int e = 0; e < 4; ++e) {
                int r = row0 + wr * 64 + mi * 16 + lkg * 4 + e;
                int c = col0 + wc * 64 + ni * 16 + lr;
                out[(size_t)r * DIM + c] = acc[mi][ni][e] + bo[c];
            }
        }
    }
}

// ---------------------------------------------------------------------------
// kv_reduce: per (b,h): kvh[e][d] = sum_n v[n,e]*k[n,d];  ksum[d] = sum_n k[n,d]
// ---------------------------------------------------------------------------
__global__ __launch_bounds__(256) void kv_reduce(const _Float16* __restrict__ k16,
                                                 const _Float16* __restrict__ v16,
                                                 float* __restrict__ kvh,
                                                 float* __restrict__ ksum)
{
    __shared__ __align__(16) _Float16 K[128][64];
    __shared__ __align__(16) _Float16 V[128][64];
    const int chunk = blockIdx.x;   // 0..7
    const int bh    = blockIdx.y;   // 0..95
    const int b = bh / 12, h = bh % 12;
    const int tid = threadIdx.x;

    const size_t base = ((size_t)b * 1024 + (size_t)chunk * 128) * DIM + h * 64;
    #pragma unroll
    for (int j = 0; j < 4; ++j) {
        int idx = j * 256 + tid;
        int r = idx >> 3, c = (idx & 7) * 8;
        *(half8_t*)&K[r][c] = *(const half8_t*)&k16[base + (size_t)r * DIM + c];
        *(half8_t*)&V[r][c] = *(const half8_t*)&v16[base + (size_t)r * DIM + c];
    }
    __syncthreads();

    const int d0 = (tid & 15) * 4;
    const int e0 = (tid >> 4) * 4;
    float acc[4][4] = {};
    #pragma unroll 4
    for (int n = 0; n < 128; ++n) {
        half4_t kd = *(const half4_t*)&K[n][d0];
        half4_t ve = *(const half4_t*)&V[n][e0];
        #pragma unroll
        for (int i = 0; i < 4; ++i)
            #pragma unroll
            for (int j = 0; j < 4; ++j)
                acc[i][j] += (float)ve[i] * (float)kd[j];
    }
    float* kvp = kvh + (size_t)bh * 64 * 64;
    #pragma unroll
    for (int i = 0; i < 4; ++i)
        #pragma unroll
        for (int j = 0; j < 4; ++j)
            atomicAdd(&kvp[(e0 + i) * 64 + d0 + j], acc[i][j]);

    if (tid < 64) {
        float s = 0.0f;
        for (int n = 0; n < 128; ++n) s += (float)K[n][tid];
        atomicAdd(&ksum[bh * 64 + tid], s);
    }
}

// ---------------------------------------------------------------------------
// attn: z = 1/(q . ksum + 1e-6); attn = (q @ kv) * z   (in-place on q16)
// ---------------------------------------------------------------------------
__global__ __launch_bounds__(256) void attn_kernel(_Float16* __restrict__ q16,
                                                   const float* __restrict__ kvh,
                                                   const float* __restrict__ ksum)
{
    __shared__ __align__(16) _Float16 Q[128][72];
    __shared__ __align__(16) _Float16 Bv[64][72];
    __shared__ float S[64];
    __shared__ float Z[128];

    const int h    = blockIdx.x;        // 0..11
    const int rb   = blockIdx.y;        // 0..255
    const int row0 = rb * 128;
    const int b    = row0 >> 12;
    const int bh   = b * 12 + h;
    const int tid  = threadIdx.x;

    #pragma unroll
    for (int j = 0; j < 4; ++j) {
        int idx = j * 256 + tid;
        int r = idx >> 3, c = (idx & 7) * 8;
        *(half8_t*)&Q[r][c] =
            *(const half8_t*)&q16[(size_t)(row0 + r) * DIM + h * 64 + c];
    }
    #pragma unroll
    for (int j = 0; j < 4; ++j) {
        int idx = j * 256 + tid;
        int r = idx >> 4, c = (idx & 15) * 4;
        float4_t f = *(const float4_t*)&kvh[((size_t)bh * 64 + r) * 64 + c];
        half4_t hh;
        #pragma unroll
        for (int e = 0; e < 4; ++e) hh[e] = (_Float16)f[e];
        *(half4_t*)&Bv[r][c] = hh;
    }
    if (tid < 64) S[tid] = ksum[bh * 64 + tid];
    __syncthreads();

    if (tid < 128) {
        float dot = 0.0f;
        #pragma unroll 8
        for (int d = 0; d < 64; ++d) dot += (float)Q[tid][d] * S[d];
        Z[tid] = 1.0f / (dot + 1e-6f);
    }
    __syncthreads();

    const int w = tid >> 6, lane = tid & 63;
    const int lr = lane & 15, lkg = lane >> 4;
    float4_t acc[2][4] = {};
    #pragma unroll
    for (int kc = 0; kc < 2; ++kc) {
        half8_t aF[2], bF[4];
        #pragma unroll
        for (int mi = 0; mi < 2; ++mi)
            aF[mi] = *(const half8_t*)&Q[w * 32 + mi * 16 + lr][kc * 32 + lkg * 8];
        #pragma unroll
        for (int ni = 0; ni < 4; ++ni)
            bF[ni] = *(const half8_t*)&Bv[ni * 16 + lr][kc * 32 + lkg * 8];
        #pragma unroll
        for (int mi = 0; mi < 2; ++mi)
            #pragma unroll
            for (int ni = 0; ni < 4; ++ni)
                acc[mi][ni] = MFMA16(aF[mi], bF[ni], acc[mi][ni]);
    }
    #pragma unroll
    for (int mi = 0; mi < 2; ++mi) {
        #pragma unroll
        for (int ni = 0; ni < 4; ++ni) {
            #pragma unroll
            for (int e = 0; e < 4; ++e) {
                int r = w * 32 + mi * 16 + lkg * 4 + e;
                float v = acc[mi][ni][e] * Z[r];
                q16[(size_t)(row0 + r) * DIM + h * 64 + ni * 16 + lr] = (_Float16)v;
            }
        }
    }
}

// ---------------------------------------------------------------------------
extern "C" void kernel_launch(void* const* d_in, const int* in_sizes, int n_in,
                              void* d_out, int out_size, void* d_ws, size_t ws_size,
                              hipStream_t stream)
{
    const float* xq  = (const float*)d_in[0];  // [8,4096,768]
    const float* xkv = (const float*)d_in[1];  // [8,1024,768]
    const float* Wq  = (const float*)d_in[2];
    const float* Wk  = (const float*)d_in[3];
    const float* Wv  = (const float*)d_in[4];
    const float* Wo  = (const float*)d_in[5];
    const float* bo  = (const float*)d_in[6];

    // ---- workspace layout (~69 MB) ----
    char* ws = (char*)d_ws;
    const size_t SZ_Q16   = (size_t)32768 * 768 * 2;   // 50,331,648
    const size_t SZ_XKV16 = (size_t)8192 * 768 * 2;    // 12,582,912
    const size_t SZ_W16   = (size_t)768 * 768 * 2;     //  1,179,648
    const size_t SZ_KVH   = (size_t)96 * 64 * 64 * 4;  //  1,572,864
    const size_t SZ_KSUM  = (size_t)96 * 64 * 4;       //     24,576

    _Float16* q16   = (_Float16*)(ws);
    _Float16* xkv16 = (_Float16*)(ws + SZ_Q16);
    _Float16* Wq16  = (_Float16*)(ws + SZ_Q16 + SZ_XKV16);            // 4 contiguous
    _Float16* Wk16  = (_Float16*)(ws + SZ_Q16 + SZ_XKV16 + SZ_W16);
    _Float16* Wv16  = (_Float16*)(ws + SZ_Q16 + SZ_XKV16 + 2 * SZ_W16);
    _Float16* Wo16  = (_Float16*)(ws + SZ_Q16 + SZ_XKV16 + 3 * SZ_W16);
    float*    kvh   = (float*)   (ws + SZ_Q16 + SZ_XKV16 + 4 * SZ_W16);
    float*    ksum  = (float*)   (ws + SZ_Q16 + SZ_XKV16 + 4 * SZ_W16 + SZ_KVH);

    // ---- d_out aliasing: xq16 consumed by proj_qkv; k16/v16 by kv_reduce;
    //      all dead before out_proj overwrites d_out. ----
    char* ob = (char*)d_out;
    _Float16* xq16 = (_Float16*)(ob);                       // 50,331,648
    _Float16* k16  = (_Float16*)(ob + 50331648);            // 12,582,912
    _Float16* v16  = (_Float16*)(ob + 50331648 + 12582912); // 12,582,912
    float*    out  = (float*)d_out;

    // 1) one fused cast + zero launch
    cast_all<<<16902, 256, 0, stream>>>(xq, xkv, Wq, Wk, Wv, Wo,
                                        xq16, xkv16, Wq16, kvh);

    // 2) fused projections: q = elu1(xq@Wq.T), k = elu1(xkv@Wk.T), v = xkv@Wv.T
    proj_qkv<<<1152, 512, 0, stream>>>(xq16, xkv16, Wq16, Wk16, Wv16,
                                       q16, k16, v16);

    // 3) linear attention
    kv_reduce<<<dim3(8, 96), 256, 0, stream>>>(k16, v16, kvh, ksum);
    attn_kernel<<<dim3(12, 256), 256, 0, stream>>>(q16, kvh, ksum);

    // 4) out = attn @ Wo.T + bo  (fp32 output)
    out_proj<<<768, 512, 0, stream>>>(q16, Wo16, bo, out);
}

// Round 19
// 212.081 us; speedup vs baseline: 1.2046x; 1.0016x over previous
//
#include <hip/hip_runtime.h>

typedef _Float16 half8_t __attribute__((ext_vector_type(8)));
typedef _Float16 half4_t __attribute__((ext_vector_type(4)));
typedef float    float4_t __attribute__((ext_vector_type(4)));

#define DIM 768

// async global->LDS, 16B per lane; LDS dest is wave-uniform base + lane*16
#define GLOAD16(g, l) __builtin_amdgcn_global_load_lds(                        \
    (const __attribute__((address_space(1))) void*)(g),                        \
    (__attribute__((address_space(3))) void*)(l), 16, 0, 0)

#define MFMA16(a, b, c) __builtin_amdgcn_mfma_f32_16x16x32_f16((a), (b), (c), 0, 0, 0)

// ---------------------------------------------------------------------------
// one fused cast launch: xq | xkv | weights | zero kvh+ksum (memset folded)
// ---------------------------------------------------------------------------
__global__ __launch_bounds__(256) void cast_all(
    const float* __restrict__ xq,  const float* __restrict__ xkv,
    const float* __restrict__ Wq,  const float* __restrict__ Wk,
    const float* __restrict__ Wv,  const float* __restrict__ Wo,
    _Float16* __restrict__ dq, _Float16* __restrict__ dkv,
    _Float16* __restrict__ dW /* 4 matrices contiguous */,
    float* __restrict__ kvz /* kvh+ksum region, 399,360 floats */)
{
    int i = blockIdx.x * 256 + threadIdx.x;
    if (i >= 4227072) {                        // zero kvh/ksum tail
        int z = i - 4227072;
        if (z < 99840) {
            float4_t zf = {0.f, 0.f, 0.f, 0.f};
            *(float4_t*)&kvz[(size_t)z * 4] = zf;
        }
        return;
    }
    const float* s; _Float16* d; int off;
    if (i < 3145728)      { s = xq;  d = dq;  off = i; }
    else if (i < 3932160) { s = xkv; d = dkv; off = i - 3145728; }
    else {
        int j = i - 3932160;                   // 0..294911
        int w = j / 73728;  off = j - w * 73728;
        s = (w == 0) ? Wq : (w == 1) ? Wk : (w == 2) ? Wv : Wo;
        d = dW + (size_t)w * 589824;
    }
    float4_t f0 = *(const float4_t*)&s[(size_t)off * 8];
    float4_t f1 = *(const float4_t*)&s[(size_t)off * 8 + 4];
    half8_t h;
    #pragma unroll
    for (int e = 0; e < 4; ++e) { h[e] = (_Float16)f0[e]; h[e + 4] = (_Float16)f1[e]; }
    *(half8_t*)&d[(size_t)off * 8] = h;
}

// ---------------------------------------------------------------------------
// gemm_1b — FINAL measured-best core (r17 verbatim; r18's pre-barrier frag
// read was a cross-wave race: vmcnt is per-wave, so gload_lds data staged by
// OTHER waves is only visible after every wave's vmcnt + the s_barrier).
// 256x128 tile, BK=64, 512 thr = 8 waves 4Mx2N (per-wave C 64x64).
// 3 LDS slots (48KB each), XOR-granule swizzle (0 conflicts), stage tile t+2
// while computing t, counted vmcnt(6) never 0 until tail, ONE barrier/tile,
// no explicit lgkm fence (compiler emits fine-grained per-consumer waits).
// ---------------------------------------------------------------------------
#define GEMM_SETUP                                                             \
    const int tid  = threadIdx.x;                                              \
    const int wid  = tid >> 6, lane = tid & 63;                                \
    const int wr   = wid >> 1;            /* 0..3 : 64-row band   */           \
    const int wc   = wid & 1;             /* 0..1 : 64-col band   */           \
    const int lr   = lane & 15;                                                \
    const int lkg  = lane >> 4;                                                \
    const int x    = lr & 7;                                                   \
    const int  srow = wid * 8 + (lane >> 3);                                   \
    const int  sg   = ((lane & 7) ^ (lane >> 3)) * 8;                          \
    const _Float16* Ast = A + (size_t)(row0 + srow) * DIM + sg;                \
    const _Float16* Bst = W + (size_t)(col0 + srow) * DIM + sg;                \
    const int ard = (wr * 64 + lr) * 64;  /* A row wr*64 + mi*16 + lr */       \
    const int brd = (wc * 64 + lr) * 64;  /* B row wc*64 + ni*16 + lr */       \
    const int g0  = (lkg ^ x) * 8;                                             \
    const int g1  = g0 ^ 32;

#define LDSA(s) (&lds[(s) * 24576])
#define LDSB(s) (&lds[(s) * 24576 + 16384])
#define STAGE_A(t, s, j) GLOAD16(Ast + (size_t)(t) * 64 + (size_t)(j) * 64 * DIM, \
                                 LDSA(s) + (j) * 4096 + wid * 512)
#define STAGE_B(t, s, j) GLOAD16(Bst + (size_t)(t) * 64 + (size_t)(j) * 64 * DIM, \
                                 LDSB(s) + (j) * 4096 + wid * 512)

__device__ __forceinline__ void gemm_1b(const _Float16* __restrict__ A,
                                        const _Float16* __restrict__ W,
                                        int row0, int col0,
                                        _Float16* lds, float4_t acc[4][4])
{
    GEMM_SETUP

    STAGE_A(0, 0, 0); STAGE_A(0, 0, 1); STAGE_A(0, 0, 2); STAGE_A(0, 0, 3);
    STAGE_B(0, 0, 0); STAGE_B(0, 0, 1);
    STAGE_A(1, 1, 0); STAGE_A(1, 1, 1); STAGE_A(1, 1, 2); STAGE_A(1, 1, 3);
    STAGE_B(1, 1, 0); STAGE_B(1, 1, 1);
    asm volatile("s_waitcnt vmcnt(6)" ::: "memory");
    __builtin_amdgcn_s_barrier();
    __builtin_amdgcn_sched_barrier(0);

    int s = 0, s2 = 2;
    for (int t = 0; t < 12; ++t) {
        const _Float16* Asl = LDSA(s);
        const _Float16* Bsl = LDSB(s);
        const bool pf = (t < 10);

        // frags: A rows wr*64 + mi*16 + lr, B rows (out-cols) wc*64 + ni*16 + lr
        half8_t af[4][2], bf[4][2];
        #pragma unroll
        for (int i = 0; i < 4; ++i) {
            af[i][0] = *(const half8_t*)&Asl[ard + i * 1024 + g0];
            af[i][1] = *(const half8_t*)&Asl[ard + i * 1024 + g1];
        }
        #pragma unroll
        for (int i = 0; i < 4; ++i) {
            bf[i][0] = *(const half8_t*)&Bsl[brd + i * 1024 + g0];
            bf[i][1] = *(const half8_t*)&Bsl[brd + i * 1024 + g1];
        }
        if (pf) {
            STAGE_A(t + 2, s2, 0); STAGE_A(t + 2, s2, 1);
            STAGE_A(t + 2, s2, 2); STAGE_A(t + 2, s2, 3);
            STAGE_B(t + 2, s2, 0); STAGE_B(t + 2, s2, 1);
        }

        // compiler emits fine-grained lgkmcnt per MFMA operand; no explicit
        // drain needed (these are plain loads, not inline-asm ds_reads).
        __builtin_amdgcn_s_setprio(1);
        #pragma unroll
        for (int mi = 0; mi < 4; ++mi)
            #pragma unroll
            for (int ni = 0; ni < 4; ++ni) {
                acc[mi][ni] = MFMA16(af[mi][0], bf[ni][0], acc[mi][ni]);
                acc[mi][ni] = MFMA16(af[mi][1], bf[ni][1], acc[mi][ni]);
            }
        __builtin_amdgcn_s_setprio(0);

        if (t < 11) {
            if (pf) asm volatile("s_waitcnt vmcnt(6)" ::: "memory");
            else    asm volatile("s_waitcnt vmcnt(0)" ::: "memory");
            __builtin_amdgcn_s_barrier();
            __builtin_amdgcn_sched_barrier(0);
        }
        s  = (s  == 2) ? 0 : s  + 1;
        s2 = (s2 == 2) ? 0 : s2 + 1;
    }
}

// ---------------------------------------------------------------------------
// Fused q/k/v projection: 1152 blocks (256x128 tiles) — gemm_1b 4Mx2N
// ---------------------------------------------------------------------------
__global__ __launch_bounds__(512) void proj_qkv(
    const _Float16* __restrict__ xq16, const _Float16* __restrict__ xkv16,
    const _Float16* __restrict__ Wq16, const _Float16* __restrict__ Wk16,
    const _Float16* __restrict__ Wv16,
    _Float16* __restrict__ q16, _Float16* __restrict__ k16,
    _Float16* __restrict__ v16)
{
    __shared__ __align__(16) _Float16 lds[3 * 24576];   // 147456 B

    const int cpx = gridDim.x >> 3;                     // 1152/8 = 144
    int bid = (blockIdx.x & 7) * cpx + (blockIdx.x >> 3);

    const _Float16 *A, *W; _Float16* O; bool elu;
    int brow, bcol;
    if (bid < 768) {
        A = xq16; W = Wq16; O = q16; elu = true;
        brow = bid / 6; bcol = bid - brow * 6;
    } else {
        int u = bid - 768;
        int mat = u / 192;  u -= mat * 192;
        A = xkv16; W = mat ? Wv16 : Wk16; O = mat ? v16 : k16; elu = !mat;
        brow = u / 6; bcol = u - brow * 6;
    }
    const int row0 = brow * 256, col0 = bcol * 128;

    float4_t acc[4][4] = {};
    gemm_1b(A, W, row0, col0, lds, acc);

    const int wid = threadIdx.x >> 6, lane = threadIdx.x & 63;
    const int wr = wid >> 1, wc = wid & 1, lr = lane & 15, lkg = lane >> 4;
    #pragma unroll
    for (int mi = 0; mi < 4; ++mi) {
        #pragma unroll
        for (int ni = 0; ni < 4; ++ni) {
            #pragma unroll
            for (int e = 0; e < 4; ++e) {
                int r = row0 + wr * 64 + mi * 16 + lkg * 4 + e;
                int c = col0 + wc * 64 + ni * 16 + lr;
                float v = acc[mi][ni][e];
                if (elu) v = (v > 0.0f) ? (v + 1.0f) : __expf(v);  // elu(x)+1
                O[(size_t)r * DIM + c] = (_Float16)v;
            }
        }
    }
}

// ---------------------------------------------------------------------------
// out = attn16 @ Wo.T + bo  (fp32 output), 768 blocks — gemm_1b 4Mx2N
// ---------------------------------------------------------------------------
__global__ __launch_bounds__(512) void out_proj(
    const _Float16* __restrict__ a16, const _Float16* __restrict__ Wo16,
    const float* __restrict__ bo, float* __restrict__ out)
{
    __shared__ __align__(16) _Float16 lds[3 * 24576];

    const int cpx = gridDim.x >> 3;                     // 768/8 = 96
    int bid = (blockIdx.x & 7) * cpx + (blockIdx.x >> 3);
    const int brow = bid / 6, bcol = bid - brow * 6;
    const int row0 = brow * 256, col0 = bcol * 128;

    float4_t acc[4][4] = {};
    gemm_1b(a16, Wo16, row0, col0, lds, acc);

    const int wid = threadIdx.x >> 6, lane = threadIdx.x & 63;
    const int wr = wid >> 1, wc = wid & 1, lr = lane & 15, lkg = lane >> 4;
    #pragma unroll
    for (int mi = 0; mi < 4; ++mi) {
        #pragma unroll
        for (int ni = 0; ni < 4; ++ni) {
            #pragma unroll
            for (int e = 0; e < 4; ++e) {
                int r = row0 + wr * 64 + mi * 16 + lkg * 4 + e;
                int c = col0 + wc * 64 + ni * 16 + lr;
                out[(size_t)r * DIM + c] = acc[mi][ni][e] + bo[c];
            }
        }
    }
}

// ---------------------------------------------------------------------------
// kv_reduce: per (b,h): kvh[e][d] = sum_n v[n,e]*k[n,d];  ksum[d] = sum_n k[n,d]
// ---------------------------------------------------------------------------
__global__ __launch_bounds__(256) void kv_reduce(const _Float16* __restrict__ k16,
                                                 const _Float16* __restrict__ v16,
                                                 float* __restrict__ kvh,
                                                 float* __restrict__ ksum)
{
    __shared__ __align__(16) _Float16 K[128][64];
    __shared__ __align__(16) _Float16 V[128][64];
    const int chunk = blockIdx.x;   // 0..7
    const int bh    = blockIdx.y;   // 0..95
    const int b = bh / 12, h = bh % 12;
    const int tid = threadIdx.x;

    const size_t base = ((size_t)b * 1024 + (size_t)chunk * 128) * DIM + h * 64;
    #pragma unroll
    for (int j = 0; j < 4; ++j) {
        int idx = j * 256 + tid;
        int r = idx >> 3, c = (idx & 7) * 8;
        *(half8_t*)&K[r][c] = *(const half8_t*)&k16[base + (size_t)r * DIM + c];
        *(half8_t*)&V[r][c] = *(const half8_t*)&v16[base + (size_t)r * DIM + c];
    }
    __syncthreads();

    const int d0 = (tid & 15) * 4;
    const int e0 = (tid >> 4) * 4;
    float acc[4][4] = {};
    #pragma unroll 4
    for (int n = 0; n < 128; ++n) {
        half4_t kd = *(const half4_t*)&K[n][d0];
        half4_t ve = *(const half4_t*)&V[n][e0];
        #pragma unroll
        for (int i = 0; i < 4; ++i)
            #pragma unroll
            for (int j = 0; j < 4; ++j)
                acc[i][j] += (float)ve[i] * (float)kd[j];
    }
    float* kvp = kvh + (size_t)bh * 64 * 64;
    #pragma unroll
    for (int i = 0; i < 4; ++i)
        #pragma unroll
        for (int j = 0; j < 4; ++j)
            atomicAdd(&kvp[(e0 + i) * 64 + d0 + j], acc[i][j]);

    if (tid < 64) {
        float s = 0.0f;
        for (int n = 0; n < 128; ++n) s += (float)K[n][tid];
        atomicAdd(&ksum[bh * 64 + tid], s);
    }
}

// ---------------------------------------------------------------------------
// attn: z = 1/(q . ksum + 1e-6); attn = (q @ kv) * z   (in-place on q16)
// ---------------------------------------------------------------------------
__global__ __launch_bounds__(256) void attn_kernel(_Float16* __restrict__ q16,
                                                   const float* __restrict__ kvh,
                                                   const float* __restrict__ ksum)
{
    __shared__ __align__(16) _Float16 Q[128][72];
    __shared__ __align__(16) _Float16 Bv[64][72];
    __shared__ float S[64];
    __shared__ float Z[128];

    const int h    = blockIdx.x;        // 0..11
    const int rb   = blockIdx.y;        // 0..255
    const int row0 = rb * 128;
    const int b    = row0 >> 12;
    const int bh   = b * 12 + h;
    const int tid  = threadIdx.x;

    #pragma unroll
    for (int j = 0; j < 4; ++j) {
        int idx = j * 256 + tid;
        int r = idx >> 3, c = (idx & 7) * 8;
        *(half8_t*)&Q[r][c] =
            *(const half8_t*)&q16[(size_t)(row0 + r) * DIM + h * 64 + c];
    }
    #pragma unroll
    for (int j = 0; j < 4; ++j) {
        int idx = j * 256 + tid;
        int r = idx >> 4, c = (idx & 15) * 4;
        float4_t f = *(const float4_t*)&kvh[((size_t)bh * 64 + r) * 64 + c];
        half4_t hh;
        #pragma unroll
        for (int e = 0; e < 4; ++e) hh[e] = (_Float16)f[e];
        *(half4_t*)&Bv[r][c] = hh;
    }
    if (tid < 64) S[tid] = ksum[bh * 64 + tid];
    __syncthreads();

    if (tid < 128) {
        float dot = 0.0f;
        #pragma unroll 8
        for (int d = 0; d < 64; ++d) dot += (float)Q[tid][d] * S[d];
        Z[tid] = 1.0f / (dot + 1e-6f);
    }
    __syncthreads();

    const int w = tid >> 6, lane = tid & 63;
    const int lr = lane & 15, lkg = lane >> 4;
    float4_t acc[2][4] = {};
    #pragma unroll
    for (int kc = 0; kc < 2; ++kc) {
        half8_t aF[2], bF[4];
        #pragma unroll
        for (int mi = 0; mi < 2; ++mi)
            aF[mi] = *(const half8_t*)&Q[w * 32 + mi * 16 + lr][kc * 32 + lkg * 8];
        #pragma unroll
        for (int ni = 0; ni < 4; ++ni)
            bF[ni] = *(const half8_t*)&Bv[ni * 16 + lr][kc * 32 + lkg * 8];
        #pragma unroll
        for (int mi = 0; mi < 2; ++mi)
            #pragma unroll
            for (int ni = 0; ni < 4; ++ni)
                acc[mi][ni] = MFMA16(aF[mi], bF[ni], acc[mi][ni]);
    }
    #pragma unroll
    for (int mi = 0; mi < 2; ++mi) {
        #pragma unroll
        for (int ni = 0; ni < 4; ++ni) {
            #pragma unroll
            for (int e = 0; e < 4; ++e) {
                int r = w * 32 + mi * 16 + lkg * 4 + e;
                float v = acc[mi][ni][e] * Z[r];
                q16[(size_t)(row0 + r) * DIM + h * 64 + ni * 16 + lr] = (_Float16)v;
            }
        }
    }
}

// ---------------------------------------------------------------------------
extern "C" void kernel_launch(void* const* d_in, const int* in_sizes, int n_in,
                              void* d_out, int out_size, void* d_ws, size_t ws_size,
                              hipStream_t stream)
{
    const float* xq  = (const float*)d_in[0];  // [8,4096,768]
    const float* xkv = (const float*)d_in[1];  // [8,1024,768]
    const float* Wq  = (const float*)d_in[2];
    const float* Wk  = (const float*)d_in[3];
    const float* Wv  = (const float*)d_in[4];
    const float* Wo  = (const float*)d_in[5];
    const float* bo  = (const float*)d_in[6];

    // ---- workspace layout (~69 MB) ----
    char* ws = (char*)d_ws;
    const size_t SZ_Q16   = (size_t)32768 * 768 * 2;   // 50,331,648
    const size_t SZ_XKV16 = (size_t)8192 * 768 * 2;    // 12,582,912
    const size_t SZ_W16   = (size_t)768 * 768 * 2;     //  1,179,648
    const size_t SZ_KVH   = (size_t)96 * 64 * 64 * 4;  //  1,572,864
    const size_t SZ_KSUM  = (size_t)96 * 64 * 4;       //     24,576

    _Float16* q16   = (_Float16*)(ws);
    _Float16* xkv16 = (_Float16*)(ws + SZ_Q16);
    _Float16* Wq16  = (_Float16*)(ws + SZ_Q16 + SZ_XKV16);            // 4 contiguous
    _Float16* Wk16  = (_Float16*)(ws + SZ_Q16 + SZ_XKV16 + SZ_W16);
    _Float16* Wv16  = (_Float16*)(ws + SZ_Q16 + SZ_XKV16 + 2 * SZ_W16);
    _Float16* Wo16  = (_Float16*)(ws + SZ_Q16 + SZ_XKV16 + 3 * SZ_W16);
    float*    kvh   = (float*)   (ws + SZ_Q16 + SZ_XKV16 + 4 * SZ_W16);
    float*    ksum  = (float*)   (ws + SZ_Q16 + SZ_XKV16 + 4 * SZ_W16 + SZ_KVH);

    // ---- d_out aliasing: xq16 consumed by proj_qkv; k16/v16 by kv_reduce;
    //      all dead before out_proj overwrites d_out. ----
    char* ob = (char*)d_out;
    _Float16* xq16 = (_Float16*)(ob);                       // 50,331,648
    _Float16* k16  = (_Float16*)(ob + 50331648);            // 12,582,912
    _Float16* v16  = (_Float16*)(ob + 50331648 + 12582912); // 12,582,912
    float*    out  = (float*)d_out;

    // 1) one fused cast + zero launch
    cast_all<<<16902, 256, 0, stream>>>(xq, xkv, Wq, Wk, Wv, Wo,
                                        xq16, xkv16, Wq16, kvh);

    // 2) fused projections: q = elu1(xq@Wq.T), k = elu1(xkv@Wk.T), v = xkv@Wv.T
    proj_qkv<<<1152, 512, 0, stream>>>(xq16, xkv16, Wq16, Wk16, Wv16,
                                       q16, k16, v16);

    // 3) linear attention
    kv_reduce<<<dim3(8, 96), 256, 0, stream>>>(k16, v16, kvh, ksum);
    attn_kernel<<<dim3(12, 256), 256, 0, stream>>>(q16, kvh, ksum);

    // 4) out = attn @ Wo.T + bo  (fp32 output)
    out_proj<<<768, 512, 0, stream>>>(q16, Wo16, bo, out);
}